// Round 12
// baseline (940.331 us; speedup 1.0000x reference)
//
#include <hip/hip_runtime.h>

#define Bg    32
#define NNg   513
#define INF   128
#define OUTF  256
#define TT    4
#define NSTEP 4
#define DEGg  16
#define Ntot  (Bg*NNg)        // 16416
#define Etot  (Ntot*DEGg)     // 262656
#define CATF  (OUTF+INF)      // 384
#define SK    1056            // 1024 + 4 cnt + 28 pad
#define NB    (Ntot*TT)       // 65664 buckets (dst*4+type)
#define NSB2  129             // cdiv(NB,512)

typedef _Float16 h8_t __attribute__((ext_vector_type(8)));
typedef _Float16 h4_t __attribute__((ext_vector_type(4)));
typedef float    f4_t __attribute__((ext_vector_type(4)));

// ---------------- elementwise ----------------
__global__ void pad_h_k(const float* __restrict__ feat, float* __restrict__ h,
                        _Float16* __restrict__ h16) {
  int idx = blockIdx.x*256 + threadIdx.x;
  if (idx >= Ntot*OUTF) return;
  int n = idx >> 8, c = idx & 255;
  float v = (c < INF) ? feat[n*INF + c] : 0.f;
  h[idx] = v;
  h16[idx] = (_Float16)v;
}

__global__ void cvt_k(const float* __restrict__ s, _Float16* __restrict__ d, int n) {
  int i = (blockIdx.x*256 + threadIdx.x) * 4;
  if (i >= n) return;
  float4 v = *reinterpret_cast<const float4*>(s + i);
  _Float16 o[4] = {(_Float16)v.x, (_Float16)v.y, (_Float16)v.z, (_Float16)v.w};
  *reinterpret_cast<ushort4*>(d + i) = *reinterpret_cast<ushort4*>(o);
}

// cb16[n][c] = c<256 ? h16[n][c] : (f16)feature[n][c-256]
__global__ void build_cb16_k(const _Float16* __restrict__ h16,
                             const float* __restrict__ feat,
                             _Float16* __restrict__ cb) {
  int idx = blockIdx.x*256 + threadIdx.x;
  if (idx >= Ntot*CATF) return;
  int n = idx / CATF, c = idx % CATF;
  cb[idx] = (c < OUTF) ? h16[n*OUTF + c] : (_Float16)feat[n*INF + (c - OUTF)];
}

__global__ void zero_int_k(int* __restrict__ p, int n) {
  int i = blockIdx.x*256 + threadIdx.x;
  if (i < n) p[i] = 0;
}

// histogram over buckets b = dst*4 + type
__global__ void hist_k(const int* __restrict__ dst, const int* __restrict__ typ,
                       int* __restrict__ cnt) {
  int e = blockIdx.x*256 + threadIdx.x;
  if (e < Etot) atomicAdd(&cnt[dst[e]*TT + typ[e]], 1);
}

// ---- 3-phase parallel exclusive scan of cnt[NB] -> rp2 ----
__global__ void scan1_k(const int* __restrict__ cnt, int* __restrict__ rp2,
                        int* __restrict__ bsum) {
  __shared__ int buf[512];
  int t = threadIdx.x;           // 512 threads
  int i = blockIdx.x*512 + t;
  int v = (i < NB) ? cnt[i] : 0;
  buf[t] = v;
  __syncthreads();
  #pragma unroll
  for (int off = 1; off < 512; off <<= 1) {
    int x = (t >= off) ? buf[t - off] : 0;
    __syncthreads();
    buf[t] += x;
    __syncthreads();
  }
  if (i < NB) rp2[i] = buf[t] - v;       // exclusive within block
  if (t == 511) bsum[blockIdx.x] = buf[511];
}

__global__ void scan2_k(int* __restrict__ bsum) {   // single block; NSB2 <= 256
  __shared__ int buf[256];
  int t = threadIdx.x;
  int v = (t < NSB2) ? bsum[t] : 0;
  buf[t] = v;
  __syncthreads();
  #pragma unroll
  for (int off = 1; off < 256; off <<= 1) {
    int x = (t >= off) ? buf[t - off] : 0;
    __syncthreads();
    buf[t] += x;
    __syncthreads();
  }
  if (t < NSB2) bsum[t] = buf[t] - v;     // exclusive block offsets
}

__global__ void scan3_k(int* __restrict__ rp2, const int* __restrict__ bsum) {
  int i = blockIdx.x*512 + threadIdx.x;
  if (i < NB) rp2[i] += bsum[blockIdx.x];
  if (i == 0) rp2[NB] = Etot;
}

// srcv[rp2[b]+pos] = esrc[e]  (store src node id directly; type implicit in bucket)
__global__ void fill_k(const int* __restrict__ dst, const int* __restrict__ typ,
                       const int* __restrict__ src, const int* __restrict__ rp2,
                       int* __restrict__ cursor, int* __restrict__ srcv) {
  int e = blockIdx.x*256 + threadIdx.x;
  if (e < Etot) {
    int b = dst[e]*TT + typ[e];
    int pos = atomicAdd(&cursor[b], 1);
    srcv[rp2[b] + pos] = src[e];
  }
}

// Type-sorted gather: s16[n][t*256+c] = sum over type-t in-edges of h16[src][c];
// s16[n][1024+t] = segment length (exact count). No predication: segments contiguous.
__global__ void gather_k(const _Float16* __restrict__ h16, const int* __restrict__ rp2,
                         const int* __restrict__ srcv, _Float16* __restrict__ s16) {
  __shared__ int src_s[128];
  int n = blockIdx.x;
  int c = threadIdx.x;  // 256
  int b0 = rp2[TT*n], e1 = rp2[TT*n+1], e2 = rp2[TT*n+2], e3 = rp2[TT*n+3], e4 = rp2[TT*n+4];
  float a0 = 0.f, a1 = 0.f, a2 = 0.f, a3 = 0.f;
  for (int base = b0; base < e4; base += 128) {
    int m = e4 - base; if (m > 128) m = 128;
    if (c < m) src_s[c] = srcv[base + c];
    __syncthreads();
    int l1 = min(max(e1 - base, 0), m);
    int l2 = min(max(e2 - base, 0), m);
    int l3 = min(max(e3 - base, 0), m);
    int i = 0;
    for (; i < l1; ++i) a0 += (float)h16[(size_t)src_s[i]*256 + c];
    for (; i < l2; ++i) a1 += (float)h16[(size_t)src_s[i]*256 + c];
    for (; i < l3; ++i) a2 += (float)h16[(size_t)src_s[i]*256 + c];
    for (; i < m;  ++i) a3 += (float)h16[(size_t)src_s[i]*256 + c];
    __syncthreads();
  }
  size_t b = (size_t)n * SK;
  s16[b + 0*256 + c] = (_Float16)a0;
  s16[b + 1*256 + c] = (_Float16)a1;
  s16[b + 2*256 + c] = (_Float16)a2;
  s16[b + 3*256 + c] = (_Float16)a3;
  if (c < 32) {
    int cv = (c == 0) ? (e1-b0) : (c == 1) ? (e2-e1) : (c == 2) ? (e3-e2) : (c == 3) ? (e4-e3) : 0;
    s16[b + 1024 + c] = (_Float16)(float)cv;
  }
}

// Wext[co][k]: k<1024 -> W_msg[k>>8][co][k&255]; k in [1024,1028) -> b_msg[(k-1024)*256+co]; else 0
__global__ void repack_wext_k(const float* __restrict__ Wmsg, const float* __restrict__ bmsg,
                              _Float16* __restrict__ wext) {
  int idx = blockIdx.x*256 + threadIdx.x;
  if (idx >= 256*SK) return;
  int co = idx / SK, k = idx % SK;
  float v;
  if (k < 1024)      { int t = k >> 8, ci = k & 255; v = Wmsg[((size_t)t*256 + co)*256 + ci]; }
  else if (k < 1028) { v = bmsg[(k - 1024)*256 + co]; }
  else               { v = 0.f; }
  wext[idx] = (_Float16)v;
}

// f16 gi/gh; 4 channels per thread
__global__ void gru_gate_k(const _Float16* __restrict__ gi, const _Float16* __restrict__ gh,
                           float* __restrict__ h, _Float16* __restrict__ h16) {
  int idx = blockIdx.x*256 + threadIdx.x;
  if (idx >= Ntot*64) return;
  int n = idx >> 6, g4 = (idx & 63) * 4;
  const _Float16* gin = gi + (size_t)n*768 + g4;
  const _Float16* ghn = gh + (size_t)n*768 + g4;
  h4_t ir = *reinterpret_cast<const h4_t*>(gin);
  h4_t iz = *reinterpret_cast<const h4_t*>(gin + 256);
  h4_t in_ = *reinterpret_cast<const h4_t*>(gin + 512);
  h4_t hr = *reinterpret_cast<const h4_t*>(ghn);
  h4_t hz = *reinterpret_cast<const h4_t*>(ghn + 256);
  h4_t hn = *reinterpret_cast<const h4_t*>(ghn + 512);
  size_t hb = (size_t)n*256 + g4;
  float4 hv = *reinterpret_cast<const float4*>(h + hb);
  float hvv[4] = {hv.x, hv.y, hv.z, hv.w};
  float ov[4];
  _Float16 ov16[4];
  #pragma unroll
  for (int j = 0; j < 4; ++j) {
    float r  = 1.f / (1.f + expf(-((float)ir[j] + (float)hr[j])));
    float z  = 1.f / (1.f + expf(-((float)iz[j] + (float)hz[j])));
    float nn = tanhf((float)in_[j] + r * (float)hn[j]);
    float o = (1.f - z) * nn + z * hvv[j];
    ov[j] = o;
    ov16[j] = (_Float16)o;
  }
  float4 os = {ov[0], ov[1], ov[2], ov[3]};
  *reinterpret_cast<float4*>(h + hb) = os;
  *reinterpret_cast<ushort4*>(h16 + hb) = *reinterpret_cast<ushort4*>(ov16);
}

template<typename IT, typename OT>
__global__ void maxpool_k(const IT* __restrict__ in, OT* __restrict__ out,
                          int Lin, int Lp, int C, int kwin) {
  int idx = blockIdx.x*256 + threadIdx.x;
  int total = Bg*Lp*C;
  if (idx >= total) return;
  int c = idx % C; int r = idx / C; int p = r % Lp; int b = r / Lp;
  const IT* base = in + ((size_t)(b*Lin + 2*p))*C + c;
  float v = (float)base[0];
  for (int w = 1; w < kwin; ++w) v = fmaxf(v, (float)base[(size_t)w*C]);
  out[idx] = (OT)v;
}

// wk16[co][k][ci] = (f16) w[co][ci][k]
__global__ void repack16_k(const float* __restrict__ w, _Float16* __restrict__ wk,
                           int Cout, int Cin, int K) {
  int idx = blockIdx.x*256 + threadIdx.x;
  int total = Cout*Cin*K;
  if (idx >= total) return;
  int ci = idx % Cin; int r = idx / Cin; int k = r % K; int co = r / K;
  wk[idx] = (_Float16)w[(co*Cin + ci)*K + k];
}

__global__ void head_k(const float* __restrict__ Y2, const float* __restrict__ Z2,
                       const float* __restrict__ wy, const float* __restrict__ by,
                       const float* __restrict__ wz, const float* __restrict__ bz,
                       float* __restrict__ out) {
  int b = blockIdx.x;
  int tid = threadIdx.x;  // 128
  __shared__ float red[128];
  float sum = 0.f;
  for (int p = tid; p < 127; p += 128) {
    const float* yr = Y2 + ((size_t)(b*127 + p))*OUTF;
    const float* zr = Z2 + ((size_t)(b*127 + p))*CATF;
    float yv = by[0], zv = bz[0];
    for (int c = 0; c < OUTF; ++c) yv = fmaf(yr[c], wy[c], yv);
    for (int c = 0; c < CATF; ++c) zv = fmaf(zr[c], wz[c], zv);
    sum += yv * zv;
  }
  red[tid] = sum;
  __syncthreads();
  for (int off = 64; off > 0; off >>= 1) {
    if (tid < off) red[tid] += red[tid + off];
    __syncthreads();
  }
  if (tid == 0) out[b] = 1.f / (1.f + expf(-red[0] / 127.f));
}

// ------------- f16 MFMA GEMM: C[m][n] = act(sum_k A[m][k]*W[n][k] + bias[n]) -------------
// Tile 128x128xK, BK=32, 256 threads = 4 waves (2x2), wave tile 64x64 = 4x4 MFMA frags.
// Staging: each thread loads 2x int4 (16 f16) for A AND for W -> full 128x32 tiles.
// A row m at A + node(m)*arstride (f16 elems), K contiguous. CT = output type (float/f16).
// N must be a multiple of 128. MAPPED: node(m) = (m/Lout)*NNodes + (m%Lout).
template<typename CT, bool RELU, bool MAPPED>
__global__ __launch_bounds__(256, 2) void hgemm(
    const _Float16* __restrict__ A, const _Float16* __restrict__ W,
    const float* __restrict__ bias, CT* __restrict__ C,
    int M, int Nout, int K, int arstride, int Lout, int NNodes) {
  __shared__ _Float16 As[128][40];   // padded: 80B row stride -> <=2-way bank aliasing (free)
  __shared__ _Float16 Ws[128][40];
  int tid = threadIdx.x;
  int lane = tid & 63, wid = tid >> 6;
  int wm = wid >> 1, wn = wid & 1;
  int l15 = lane & 15, l4 = lane >> 4;
  int m0 = blockIdx.x * 128, n0 = blockIdx.y * 128;

  // staging: A/W each 128 rows x 32 f16; 2 threads/row x 16 f16 (2x int4) per tile
  int s_row = tid >> 1;
  int s_col = (tid & 1) * 16;
  int m_s = m0 + s_row;
  bool a_ok = (m_s < M);
  int mc = a_ok ? m_s : (M - 1);
  int node = MAPPED ? (mc / Lout) * NNodes + (mc % Lout) : mc;
  const _Float16* a_src = A + (size_t)node * arstride + s_col;
  const _Float16* w_src = W + (size_t)(n0 + s_row) * K + s_col;

  f4_t acc[4][4] = {};

  for (int k0 = 0; k0 < K; k0 += 32) {
    if (k0) __syncthreads();
    int4 va0 = {0,0,0,0}, va1 = {0,0,0,0};
    if (a_ok) {
      const int4* ga = reinterpret_cast<const int4*>(a_src + k0);
      va0 = ga[0]; va1 = ga[1];
    }
    const int4* gw = reinterpret_cast<const int4*>(w_src + k0);
    int4 vw0 = gw[0], vw1 = gw[1];
    *reinterpret_cast<int4*>(&As[s_row][s_col])     = va0;
    *reinterpret_cast<int4*>(&As[s_row][s_col + 8]) = va1;
    *reinterpret_cast<int4*>(&Ws[s_row][s_col])     = vw0;
    *reinterpret_cast<int4*>(&Ws[s_row][s_col + 8]) = vw1;
    __syncthreads();

    h8_t af[4], bf[4];
    #pragma unroll
    for (int fm = 0; fm < 4; ++fm)
      af[fm] = *reinterpret_cast<const h8_t*>(&As[wm*64 + fm*16 + l15][l4*8]);
    #pragma unroll
    for (int fn = 0; fn < 4; ++fn)
      bf[fn] = *reinterpret_cast<const h8_t*>(&Ws[wn*64 + fn*16 + l15][l4*8]);
    #pragma unroll
    for (int fm = 0; fm < 4; ++fm)
      #pragma unroll
      for (int fn = 0; fn < 4; ++fn)
        acc[fm][fn] = __builtin_amdgcn_mfma_f32_16x16x32_f16(af[fm], bf[fn], acc[fm][fn], 0, 0, 0);
  }

  // epilogue: D row = (lane>>4)*4 + reg, col = lane&15  (verified C/D layout)
  #pragma unroll
  for (int fn = 0; fn < 4; ++fn) {
    int col = n0 + wn*64 + fn*16 + l15;
    float bv = bias[col];
    #pragma unroll
    for (int fm = 0; fm < 4; ++fm) {
      #pragma unroll
      for (int i = 0; i < 4; ++i) {
        int m = m0 + wm*64 + fm*16 + l4*4 + i;
        if (m >= M) continue;
        float v = acc[fm][fn][i] + bv;
        if (RELU) v = fmaxf(v, 0.f);
        C[(size_t)m * Nout + col] = (CT)v;
      }
    }
  }
}

static inline int cdiv(int x, int y) { return (x + y - 1) / y; }

extern "C" void kernel_launch(void* const* d_in, const int* in_sizes, int n_in,
                              void* d_out, int out_size, void* d_ws, size_t ws_size,
                              hipStream_t stream) {
  const float* feature  = (const float*)d_in[0];
  const float* W_msg    = (const float*)d_in[1];   // [4,256,256]
  const float* b_msg    = (const float*)d_in[2];   // [1024]
  const float* w_ih     = (const float*)d_in[3];
  const float* w_hh     = (const float*)d_in[4];
  const float* b_ih     = (const float*)d_in[5];
  const float* b_hh     = (const float*)d_in[6];
  const float* conv1_w  = (const float*)d_in[7];
  const float* conv1_b  = (const float*)d_in[8];
  const float* conv2_w  = (const float*)d_in[9];   // [256,256,1]
  const float* conv2_b  = (const float*)d_in[10];
  const float* convc1_w = (const float*)d_in[11];
  const float* convc1_b = (const float*)d_in[12];
  const float* convc2_w = (const float*)d_in[13];
  const float* convc2_b = (const float*)d_in[14];
  const float* mlpy_w   = (const float*)d_in[15];
  const float* mlpy_b   = (const float*)d_in[16];
  const float* mlpz_w   = (const float*)d_in[17];
  const float* mlpz_b   = (const float*)d_in[18];
  const int*   esrc     = (const int*)d_in[19];
  const int*   edst     = (const int*)d_in[20];
  const int*   etyp     = (const int*)d_in[21];
  float* out = (float*)d_out;

  // ---- workspace layout (bytes); peak ~128 MB ----
  char* base = (char*)d_ws;
  size_t off = 0;
  auto alloc = [&](size_t bytes) { void* p = base + off; off = (off + bytes + 255) & ~(size_t)255; return p; };
  float*    h      = (float*)   alloc((size_t)Ntot*OUTF*4);    // 16.8 MB
  _Float16* h16    = (_Float16*)alloc((size_t)Ntot*OUTF*2);    //  8.4 MB
  _Float16* Wext16 = (_Float16*)alloc((size_t)256*SK*2);       //  0.54 MB
  _Float16* wih16  = (_Float16*)alloc((size_t)768*256*2);
  _Float16* whh16  = (_Float16*)alloc((size_t)768*256*2);
  float*    bias0  = (float*)   alloc(256*4);                  // zeros
  int* rp2    = (int*)alloc((NB+1)*4);                         // bucket rowptr
  int* cnt    = (int*)alloc(NB*4);
  int* bsum   = (int*)alloc(NSB2*4);
  int* srcv   = (int*)alloc((size_t)Etot*4);                   // type-sorted src ids
  char* big   = (char*)alloc((size_t)Ntot*1536*4);             // 100.9 MB shared region
  // GGNN phase views of big (f16 gi/gh):
  //   gi  = big[0 : 25.2MB)     (f16, N*768)
  //   gh  = big[25.2 : 50.4MB)  (f16, N*768)
  //   s16 = big[50.4 : 85.1MB)  (f16, N*1056)
  //   a16 = big[85.1 : 93.5MB)  (f16, N*256)
  _Float16* gi  = (_Float16*)big;
  _Float16* gh  = gi + (size_t)Ntot*768;
  _Float16* s16 = (_Float16*)(big + (size_t)Ntot*768*4);
  _Float16* a16 = s16 + (size_t)Ntot*SK;
  // conv phase views of big (GGNN scratch dead; ~77 MB <= 100.9MB)
  float*    Y2   = (float*)big;                              // 32*127*256 f32
  float*    Z2   = Y2 + (size_t)Bg*127*OUTF;                 // 32*127*384 f32
  _Float16* y1   = (_Float16*)(Z2 + (size_t)Bg*127*CATF);    // 32*511*256 f16
  float*    y2   = (float*)(y1 + (size_t)Bg*511*OUTF);       // 32*255*256 f32
  _Float16* p1   = (_Float16*)(y2 + (size_t)Bg*255*OUTF);    // 32*255*256 f16
  _Float16* cb16 = p1 + (size_t)Bg*255*OUTF;                 // 16416*384 f16
  _Float16* z1   = cb16 + (size_t)Ntot*CATF;                 // 32*511*384 f16
  float*    z2   = (float*)(z1 + (size_t)Bg*511*CATF);       // 32*254*384 f32
  _Float16* pz1  = (_Float16*)(z2 + (size_t)Bg*254*CATF);    // 32*255*384 f16
  _Float16* wk1  = pz1 + (size_t)Bg*255*CATF;                // 256*768  f16 (conv-phase only)
  _Float16* wkc1 = wk1 + (size_t)256*768;                    // 384*1152 f16
  _Float16* wkc2 = wkc1 + (size_t)384*1152;                  // 384*768  f16
  _Float16* c2w16= wkc2 + (size_t)384*768;                   // 256*256  f16

  dim3 blk(256);

  // 1. h = pad(feature); weight conversions; zero bias
  pad_h_k<<<cdiv(Ntot*OUTF,256), blk, 0, stream>>>(feature, h, h16);
  repack_wext_k<<<cdiv(256*SK,256), blk, 0, stream>>>(W_msg, b_msg, Wext16);
  cvt_k<<<cdiv(768*256/4,256), blk, 0, stream>>>(w_ih, wih16, 768*256);
  cvt_k<<<cdiv(768*256/4,256), blk, 0, stream>>>(w_hh, whh16, 768*256);
  hipMemsetAsync(bias0, 0, 256*4, stream);

  // 2. type-sorted CSR: bucket = dst*4 + type
  zero_int_k<<<cdiv(NB,256), blk, 0, stream>>>(cnt, NB);
  hist_k<<<cdiv(Etot,256), blk, 0, stream>>>(edst, etyp, cnt);
  scan1_k<<<NSB2, 512, 0, stream>>>(cnt, rp2, bsum);
  scan2_k<<<1, blk, 0, stream>>>(bsum);
  scan3_k<<<NSB2, 512, 0, stream>>>(rp2, bsum);
  zero_int_k<<<cdiv(NB,256), blk, 0, stream>>>(cnt, NB);
  fill_k<<<cdiv(Etot,256), blk, 0, stream>>>(edst, etyp, esrc, rp2, cnt, srcv);

  // 3. GGNN steps: type-sorted gather, then a = s @ Wext^T (bias via K-ext)
  for (int s = 0; s < NSTEP; ++s) {
    gather_k<<<Ntot, blk, 0, stream>>>(h16, rp2, srcv, s16);
    hgemm<_Float16,false,false><<<dim3(cdiv(Ntot,128), 2), blk, 0, stream>>>(
        s16, Wext16, bias0, a16, Ntot, 256, SK, SK, 0, 0);
    hgemm<_Float16,false,false><<<dim3(cdiv(Ntot,128), 6), blk, 0, stream>>>(
        a16, wih16, b_ih, gi, Ntot, 768, 256, 256, 0, 0);
    hgemm<_Float16,false,false><<<dim3(cdiv(Ntot,128), 6), blk, 0, stream>>>(
        h16, whh16, b_hh, gh, Ntot, 768, 256, 256, 0, 0);
    gru_gate_k<<<cdiv(Ntot*64,256), blk, 0, stream>>>(gi, gh, h, h16);
  }

  // 4. conv-head weight repacks (conv-phase spare of big)
  repack16_k<<<cdiv(256*256*3,256), blk, 0, stream>>>(conv1_w,  wk1,  256, 256, 3);
  repack16_k<<<cdiv(384*384*3,256), blk, 0, stream>>>(convc1_w, wkc1, 384, 384, 3);
  repack16_k<<<cdiv(384*384*2,256), blk, 0, stream>>>(convc2_w, wkc2, 384, 384, 2);
  cvt_k<<<cdiv(256*256/4,256), blk, 0, stream>>>(conv2_w, c2w16, 256*256);

  // 5. Y head: conv1(K=3) -> pool3 -> conv2(K=1) -> pool2
  hgemm<_Float16,true,true><<<dim3(cdiv(Bg*511,128), 2), blk, 0, stream>>>(
      h16, wk1, conv1_b, y1, Bg*511, 256, 768, 256, 511, NNg);
  maxpool_k<_Float16,_Float16><<<cdiv(Bg*255*256,256), blk, 0, stream>>>(y1, p1, 511, 255, 256, 3);
  hgemm<float,true,false><<<dim3(cdiv(Bg*255,128), 2), blk, 0, stream>>>(
      p1, c2w16, conv2_b, y2, Bg*255, 256, 256, 256, 0, 0);
  maxpool_k<float,float><<<cdiv(Bg*127*256,256), blk, 0, stream>>>(y2, Y2, 255, 127, 256, 2);

  // 6. Z head: cb16=concat(h16,(f16)feature); convc1(K=3) -> pool3 -> convc2(K=2) -> pool2
  build_cb16_k<<<cdiv(Ntot*CATF,256), blk, 0, stream>>>(h16, feature, cb16);
  hgemm<_Float16,true,true><<<dim3(cdiv(Bg*511,128), 3), blk, 0, stream>>>(
      cb16, wkc1, convc1_b, z1, Bg*511, 384, 1152, 384, 511, NNg);
  maxpool_k<_Float16,_Float16><<<cdiv(Bg*255*384,256), blk, 0, stream>>>(z1, pz1, 511, 255, 384, 3);
  hgemm<float,true,true><<<dim3(cdiv(Bg*254,128), 3), blk, 0, stream>>>(
      pz1, wkc2, convc2_b, z2, Bg*254, 384, 768, 384, 254, 255);
  maxpool_k<float,float><<<cdiv(Bg*127*384,256), blk, 0, stream>>>(z2, Z2, 254, 127, 384, 2);

  // 7. head
  head_k<<<Bg, 128, 0, stream>>>(Y2, Z2, mlpy_w, mlpy_b, mlpz_w, mlpz_b, out);
}

// Round 13
// 877.493 us; speedup vs baseline: 1.0716x; 1.0716x over previous
//
#include <hip/hip_runtime.h>

#define Bg    32
#define NNg   513
#define INF   128
#define OUTF  256
#define TT    4
#define NSTEP 4
#define DEGg  16
#define Ntot  (Bg*NNg)        // 16416
#define Etot  (Ntot*DEGg)     // 262656
#define CATF  (OUTF+INF)      // 384
#define SK    1056            // 1024 + 4 cnt + 28 pad
#define NB    (Ntot*TT)       // 65664 buckets (dst*4+type)
#define NSB2  129             // cdiv(NB,512)

typedef _Float16 h8_t __attribute__((ext_vector_type(8)));
typedef _Float16 h4_t __attribute__((ext_vector_type(4)));
typedef float    f4_t __attribute__((ext_vector_type(4)));

// ---------------- elementwise ----------------
__global__ void pad_h_k(const float* __restrict__ feat, float* __restrict__ h,
                        _Float16* __restrict__ h16) {
  int idx = blockIdx.x*256 + threadIdx.x;
  if (idx >= Ntot*OUTF) return;
  int n = idx >> 8, c = idx & 255;
  float v = (c < INF) ? feat[n*INF + c] : 0.f;
  h[idx] = v;
  h16[idx] = (_Float16)v;
}

__global__ void cvt_k(const float* __restrict__ s, _Float16* __restrict__ d, int n) {
  int i = (blockIdx.x*256 + threadIdx.x) * 4;
  if (i >= n) return;
  float4 v = *reinterpret_cast<const float4*>(s + i);
  _Float16 o[4] = {(_Float16)v.x, (_Float16)v.y, (_Float16)v.z, (_Float16)v.w};
  *reinterpret_cast<ushort4*>(d + i) = *reinterpret_cast<ushort4*>(o);
}

// cb16[n][c] = c<256 ? h16[n][c] : (f16)feature[n][c-256]
__global__ void build_cb16_k(const _Float16* __restrict__ h16,
                             const float* __restrict__ feat,
                             _Float16* __restrict__ cb) {
  int idx = blockIdx.x*256 + threadIdx.x;
  if (idx >= Ntot*CATF) return;
  int n = idx / CATF, c = idx % CATF;
  cb[idx] = (c < OUTF) ? h16[n*OUTF + c] : (_Float16)feat[n*INF + (c - OUTF)];
}

__global__ void zero_int_k(int* __restrict__ p, int n) {
  int i = blockIdx.x*256 + threadIdx.x;
  if (i < n) p[i] = 0;
}

// histogram over buckets b = dst*4 + type
__global__ void hist_k(const int* __restrict__ dst, const int* __restrict__ typ,
                       int* __restrict__ cnt) {
  int e = blockIdx.x*256 + threadIdx.x;
  if (e < Etot) atomicAdd(&cnt[dst[e]*TT + typ[e]], 1);
}

// ---- 3-phase parallel exclusive scan of cnt[NB] -> rp2 ----
__global__ void scan1_k(const int* __restrict__ cnt, int* __restrict__ rp2,
                        int* __restrict__ bsum) {
  __shared__ int buf[512];
  int t = threadIdx.x;           // 512 threads
  int i = blockIdx.x*512 + t;
  int v = (i < NB) ? cnt[i] : 0;
  buf[t] = v;
  __syncthreads();
  #pragma unroll
  for (int off = 1; off < 512; off <<= 1) {
    int x = (t >= off) ? buf[t - off] : 0;
    __syncthreads();
    buf[t] += x;
    __syncthreads();
  }
  if (i < NB) rp2[i] = buf[t] - v;       // exclusive within block
  if (t == 511) bsum[blockIdx.x] = buf[511];
}

__global__ void scan2_k(int* __restrict__ bsum) {   // single block; NSB2 <= 256
  __shared__ int buf[256];
  int t = threadIdx.x;
  int v = (t < NSB2) ? bsum[t] : 0;
  buf[t] = v;
  __syncthreads();
  #pragma unroll
  for (int off = 1; off < 256; off <<= 1) {
    int x = (t >= off) ? buf[t - off] : 0;
    __syncthreads();
    buf[t] += x;
    __syncthreads();
  }
  if (t < NSB2) bsum[t] = buf[t] - v;     // exclusive block offsets
}

__global__ void scan3_k(int* __restrict__ rp2, const int* __restrict__ bsum) {
  int i = blockIdx.x*512 + threadIdx.x;
  if (i < NB) rp2[i] += bsum[blockIdx.x];
  if (i == 0) rp2[NB] = Etot;
}

// srcv[rp2[b]+pos] = esrc[e]  (store src node id directly; type implicit in bucket)
__global__ void fill_k(const int* __restrict__ dst, const int* __restrict__ typ,
                       const int* __restrict__ src, const int* __restrict__ rp2,
                       int* __restrict__ cursor, int* __restrict__ srcv) {
  int e = blockIdx.x*256 + threadIdx.x;
  if (e < Etot) {
    int b = dst[e]*TT + typ[e];
    int pos = atomicAdd(&cursor[b], 1);
    srcv[rp2[b] + pos] = src[e];
  }
}

// Type-sorted gather, segment loops hand-unrolled x4 for load ILP.
// s16[n][t*256+c] = sum over type-t in-edges of h16[src][c]; s16[n][1024+t] = count.
__global__ void gather_k(const _Float16* __restrict__ h16, const int* __restrict__ rp2,
                         const int* __restrict__ srcv, _Float16* __restrict__ s16) {
  __shared__ int src_s[128];
  int n = blockIdx.x;
  int c = threadIdx.x;  // 256
  int b0 = rp2[TT*n], e1 = rp2[TT*n+1], e2 = rp2[TT*n+2], e3 = rp2[TT*n+3], e4 = rp2[TT*n+4];
  float a0 = 0.f, a1 = 0.f, a2 = 0.f, a3 = 0.f;
  for (int base = b0; base < e4; base += 128) {
    int m = e4 - base; if (m > 128) m = 128;
    if (c < m) src_s[c] = srcv[base + c];
    __syncthreads();
    int s1 = min(max(e1 - base, 0), m);
    int s2 = min(max(e2 - base, 0), m);
    int s3 = min(max(e3 - base, 0), m);
#define SEG(ACC, ST, EN)                                                   \
    {                                                                      \
      int i = (ST);                                                        \
      for (; i + 4 <= (EN); i += 4) {                                      \
        float v0 = (float)h16[(size_t)src_s[i]  *256 + c];                 \
        float v1 = (float)h16[(size_t)src_s[i+1]*256 + c];                 \
        float v2 = (float)h16[(size_t)src_s[i+2]*256 + c];                 \
        float v3 = (float)h16[(size_t)src_s[i+3]*256 + c];                 \
        ACC += (v0 + v1) + (v2 + v3);                                      \
      }                                                                    \
      for (; i < (EN); ++i) ACC += (float)h16[(size_t)src_s[i]*256 + c];   \
    }
    SEG(a0, 0,  s1)
    SEG(a1, s1, s2)
    SEG(a2, s2, s3)
    SEG(a3, s3, m)
#undef SEG
    __syncthreads();
  }
  size_t b = (size_t)n * SK;
  s16[b + 0*256 + c] = (_Float16)a0;
  s16[b + 1*256 + c] = (_Float16)a1;
  s16[b + 2*256 + c] = (_Float16)a2;
  s16[b + 3*256 + c] = (_Float16)a3;
  if (c < 32) {
    int cv = (c == 0) ? (e1-b0) : (c == 1) ? (e2-e1) : (c == 2) ? (e3-e2) : (c == 3) ? (e4-e3) : 0;
    s16[b + 1024 + c] = (_Float16)(float)cv;
  }
}

// Wext[co][k]: k<1024 -> W_msg[k>>8][co][k&255]; k in [1024,1028) -> b_msg[(k-1024)*256+co]; else 0
__global__ void repack_wext_k(const float* __restrict__ Wmsg, const float* __restrict__ bmsg,
                              _Float16* __restrict__ wext) {
  int idx = blockIdx.x*256 + threadIdx.x;
  if (idx >= 256*SK) return;
  int co = idx / SK, k = idx % SK;
  float v;
  if (k < 1024)      { int t = k >> 8, ci = k & 255; v = Wmsg[((size_t)t*256 + co)*256 + ci]; }
  else if (k < 1028) { v = bmsg[(k - 1024)*256 + co]; }
  else               { v = 0.f; }
  wext[idx] = (_Float16)v;
}

// f16 gi/gh; 4 channels per thread
__global__ void gru_gate_k(const _Float16* __restrict__ gi, const _Float16* __restrict__ gh,
                           float* __restrict__ h, _Float16* __restrict__ h16) {
  int idx = blockIdx.x*256 + threadIdx.x;
  if (idx >= Ntot*64) return;
  int n = idx >> 6, g4 = (idx & 63) * 4;
  const _Float16* gin = gi + (size_t)n*768 + g4;
  const _Float16* ghn = gh + (size_t)n*768 + g4;
  h4_t ir = *reinterpret_cast<const h4_t*>(gin);
  h4_t iz = *reinterpret_cast<const h4_t*>(gin + 256);
  h4_t in_ = *reinterpret_cast<const h4_t*>(gin + 512);
  h4_t hr = *reinterpret_cast<const h4_t*>(ghn);
  h4_t hz = *reinterpret_cast<const h4_t*>(ghn + 256);
  h4_t hn = *reinterpret_cast<const h4_t*>(ghn + 512);
  size_t hb = (size_t)n*256 + g4;
  float4 hv = *reinterpret_cast<const float4*>(h + hb);
  float hvv[4] = {hv.x, hv.y, hv.z, hv.w};
  float ov[4];
  _Float16 ov16[4];
  #pragma unroll
  for (int j = 0; j < 4; ++j) {
    float r  = 1.f / (1.f + expf(-((float)ir[j] + (float)hr[j])));
    float z  = 1.f / (1.f + expf(-((float)iz[j] + (float)hz[j])));
    float nn = tanhf((float)in_[j] + r * (float)hn[j]);
    float o = (1.f - z) * nn + z * hvv[j];
    ov[j] = o;
    ov16[j] = (_Float16)o;
  }
  float4 os = {ov[0], ov[1], ov[2], ov[3]};
  *reinterpret_cast<float4*>(h + hb) = os;
  *reinterpret_cast<ushort4*>(h16 + hb) = *reinterpret_cast<ushort4*>(ov16);
}

template<typename IT, typename OT>
__global__ void maxpool_k(const IT* __restrict__ in, OT* __restrict__ out,
                          int Lin, int Lp, int C, int kwin) {
  int idx = blockIdx.x*256 + threadIdx.x;
  int total = Bg*Lp*C;
  if (idx >= total) return;
  int c = idx % C; int r = idx / C; int p = r % Lp; int b = r / Lp;
  const IT* base = in + ((size_t)(b*Lin + 2*p))*C + c;
  float v = (float)base[0];
  for (int w = 1; w < kwin; ++w) v = fmaxf(v, (float)base[(size_t)w*C]);
  out[idx] = (OT)v;
}

// wk16[co][k][ci] = (f16) w[co][ci][k]
__global__ void repack16_k(const float* __restrict__ w, _Float16* __restrict__ wk,
                           int Cout, int Cin, int K) {
  int idx = blockIdx.x*256 + threadIdx.x;
  int total = Cout*Cin*K;
  if (idx >= total) return;
  int ci = idx % Cin; int r = idx / Cin; int k = r % K; int co = r / K;
  wk[idx] = (_Float16)w[(co*Cin + ci)*K + k];
}

__global__ void head_k(const float* __restrict__ Y2, const float* __restrict__ Z2,
                       const float* __restrict__ wy, const float* __restrict__ by,
                       const float* __restrict__ wz, const float* __restrict__ bz,
                       float* __restrict__ out) {
  int b = blockIdx.x;
  int tid = threadIdx.x;  // 128
  __shared__ float red[128];
  float sum = 0.f;
  for (int p = tid; p < 127; p += 128) {
    const float* yr = Y2 + ((size_t)(b*127 + p))*OUTF;
    const float* zr = Z2 + ((size_t)(b*127 + p))*CATF;
    float yv = by[0], zv = bz[0];
    for (int c = 0; c < OUTF; ++c) yv = fmaf(yr[c], wy[c], yv);
    for (int c = 0; c < CATF; ++c) zv = fmaf(zr[c], wz[c], zv);
    sum += yv * zv;
  }
  red[tid] = sum;
  __syncthreads();
  for (int off = 64; off > 0; off >>= 1) {
    if (tid < off) red[tid] += red[tid + off];
    __syncthreads();
  }
  if (tid == 0) out[b] = 1.f / (1.f + expf(-red[0] / 127.f));
}

// ------------- f16 MFMA GEMM: C[m][n] = act(sum_k A[m][k]*W[n][k] + bias[n]) -------------
// Tile 128x128xK, BK=32, 256 threads = 4 waves (2x2), wave tile 64x64 = 4x4 MFMA frags.
// Staging: each thread loads 2x int4 (16 f16) for A AND for W -> full 128x32 tiles.
// A row m at A + node(m)*arstride (f16 elems), K contiguous. CT = output type (float/f16).
// N must be a multiple of 128. MAPPED: node(m) = (m/Lout)*NNodes + (m%Lout).
template<typename CT, bool RELU, bool MAPPED>
__global__ __launch_bounds__(256, 2) void hgemm(
    const _Float16* __restrict__ A, const _Float16* __restrict__ W,
    const float* __restrict__ bias, CT* __restrict__ C,
    int M, int Nout, int K, int arstride, int Lout, int NNodes) {
  __shared__ _Float16 As[128][40];   // padded: 80B row stride -> <=2-way bank aliasing (free)
  __shared__ _Float16 Ws[128][40];
  int tid = threadIdx.x;
  int lane = tid & 63, wid = tid >> 6;
  int wm = wid >> 1, wn = wid & 1;
  int l15 = lane & 15, l4 = lane >> 4;
  int m0 = blockIdx.x * 128, n0 = blockIdx.y * 128;

  // staging: A/W each 128 rows x 32 f16; 2 threads/row x 16 f16 (2x int4) per tile
  int s_row = tid >> 1;
  int s_col = (tid & 1) * 16;
  int m_s = m0 + s_row;
  bool a_ok = (m_s < M);
  int mc = a_ok ? m_s : (M - 1);
  int node = MAPPED ? (mc / Lout) * NNodes + (mc % Lout) : mc;
  const _Float16* a_src = A + (size_t)node * arstride + s_col;
  const _Float16* w_src = W + (size_t)(n0 + s_row) * K + s_col;

  f4_t acc[4][4] = {};

  for (int k0 = 0; k0 < K; k0 += 32) {
    if (k0) __syncthreads();
    int4 va0 = {0,0,0,0}, va1 = {0,0,0,0};
    if (a_ok) {
      const int4* ga = reinterpret_cast<const int4*>(a_src + k0);
      va0 = ga[0]; va1 = ga[1];
    }
    const int4* gw = reinterpret_cast<const int4*>(w_src + k0);
    int4 vw0 = gw[0], vw1 = gw[1];
    *reinterpret_cast<int4*>(&As[s_row][s_col])     = va0;
    *reinterpret_cast<int4*>(&As[s_row][s_col + 8]) = va1;
    *reinterpret_cast<int4*>(&Ws[s_row][s_col])     = vw0;
    *reinterpret_cast<int4*>(&Ws[s_row][s_col + 8]) = vw1;
    __syncthreads();

    h8_t af[4], bf[4];
    #pragma unroll
    for (int fm = 0; fm < 4; ++fm)
      af[fm] = *reinterpret_cast<const h8_t*>(&As[wm*64 + fm*16 + l15][l4*8]);
    #pragma unroll
    for (int fn = 0; fn < 4; ++fn)
      bf[fn] = *reinterpret_cast<const h8_t*>(&Ws[wn*64 + fn*16 + l15][l4*8]);
    #pragma unroll
    for (int fm = 0; fm < 4; ++fm)
      #pragma unroll
      for (int fn = 0; fn < 4; ++fn)
        acc[fm][fn] = __builtin_amdgcn_mfma_f32_16x16x32_f16(af[fm], bf[fn], acc[fm][fn], 0, 0, 0);
  }

  // epilogue: D row = (lane>>4)*4 + reg, col = lane&15  (verified C/D layout)
  #pragma unroll
  for (int fn = 0; fn < 4; ++fn) {
    int col = n0 + wn*64 + fn*16 + l15;
    float bv = bias[col];
    #pragma unroll
    for (int fm = 0; fm < 4; ++fm) {
      #pragma unroll
      for (int i = 0; i < 4; ++i) {
        int m = m0 + wm*64 + fm*16 + l4*4 + i;
        if (m >= M) continue;
        float v = acc[fm][fn][i] + bv;
        if (RELU) v = fmaxf(v, 0.f);
        C[(size_t)m * Nout + col] = (CT)v;
      }
    }
  }
}

static inline int cdiv(int x, int y) { return (x + y - 1) / y; }

extern "C" void kernel_launch(void* const* d_in, const int* in_sizes, int n_in,
                              void* d_out, int out_size, void* d_ws, size_t ws_size,
                              hipStream_t stream) {
  const float* feature  = (const float*)d_in[0];
  const float* W_msg    = (const float*)d_in[1];   // [4,256,256]
  const float* b_msg    = (const float*)d_in[2];   // [1024]
  const float* w_ih     = (const float*)d_in[3];
  const float* w_hh     = (const float*)d_in[4];
  const float* b_ih     = (const float*)d_in[5];
  const float* b_hh     = (const float*)d_in[6];
  const float* conv1_w  = (const float*)d_in[7];
  const float* conv1_b  = (const float*)d_in[8];
  const float* conv2_w  = (const float*)d_in[9];   // [256,256,1]
  const float* conv2_b  = (const float*)d_in[10];
  const float* convc1_w = (const float*)d_in[11];
  const float* convc1_b = (const float*)d_in[12];
  const float* convc2_w = (const float*)d_in[13];
  const float* convc2_b = (const float*)d_in[14];
  const float* mlpy_w   = (const float*)d_in[15];
  const float* mlpy_b   = (const float*)d_in[16];
  const float* mlpz_w   = (const float*)d_in[17];
  const float* mlpz_b   = (const float*)d_in[18];
  const int*   esrc     = (const int*)d_in[19];
  const int*   edst     = (const int*)d_in[20];
  const int*   etyp     = (const int*)d_in[21];
  float* out = (float*)d_out;

  // ---- workspace layout (bytes); peak ~128 MB ----
  char* base = (char*)d_ws;
  size_t off = 0;
  auto alloc = [&](size_t bytes) { void* p = base + off; off = (off + bytes + 255) & ~(size_t)255; return p; };
  float*    h      = (float*)   alloc((size_t)Ntot*OUTF*4);    // 16.8 MB
  _Float16* h16    = (_Float16*)alloc((size_t)Ntot*OUTF*2);    //  8.4 MB
  _Float16* Wext16 = (_Float16*)alloc((size_t)256*SK*2);       //  0.54 MB
  _Float16* wih16  = (_Float16*)alloc((size_t)768*256*2);
  _Float16* whh16  = (_Float16*)alloc((size_t)768*256*2);
  float*    bias0  = (float*)   alloc(256*4);                  // zeros
  int* rp2    = (int*)alloc((NB+1)*4);                         // bucket rowptr
  int* cnt    = (int*)alloc(NB*4);
  int* bsum   = (int*)alloc(NSB2*4);
  int* srcv   = (int*)alloc((size_t)Etot*4);                   // type-sorted src ids
  char* big   = (char*)alloc((size_t)Ntot*1536*4);             // 100.9 MB shared region
  // GGNN phase views of big (f16 gi/gh):
  //   gi  = big[0 : 25.2MB)     (f16, N*768)
  //   gh  = big[25.2 : 50.4MB)  (f16, N*768)
  //   s16 = big[50.4 : 85.1MB)  (f16, N*1056)
  //   a16 = big[85.1 : 93.5MB)  (f16, N*256)
  _Float16* gi  = (_Float16*)big;
  _Float16* gh  = gi + (size_t)Ntot*768;
  _Float16* s16 = (_Float16*)(big + (size_t)Ntot*768*4);
  _Float16* a16 = s16 + (size_t)Ntot*SK;
  // conv phase views of big (GGNN scratch dead; ~77 MB <= 100.9MB)
  float*    Y2   = (float*)big;                              // 32*127*256 f32
  float*    Z2   = Y2 + (size_t)Bg*127*OUTF;                 // 32*127*384 f32
  _Float16* y1   = (_Float16*)(Z2 + (size_t)Bg*127*CATF);    // 32*511*256 f16
  float*    y2   = (float*)(y1 + (size_t)Bg*511*OUTF);       // 32*255*256 f32
  _Float16* p1   = (_Float16*)(y2 + (size_t)Bg*255*OUTF);    // 32*255*256 f16
  _Float16* cb16 = p1 + (size_t)Bg*255*OUTF;                 // 16416*384 f16
  _Float16* z1   = cb16 + (size_t)Ntot*CATF;                 // 32*511*384 f16
  float*    z2   = (float*)(z1 + (size_t)Bg*511*CATF);       // 32*254*384 f32
  _Float16* pz1  = (_Float16*)(z2 + (size_t)Bg*254*CATF);    // 32*255*384 f16
  _Float16* wk1  = pz1 + (size_t)Bg*255*CATF;                // 256*768  f16 (conv-phase only)
  _Float16* wkc1 = wk1 + (size_t)256*768;                    // 384*1152 f16
  _Float16* wkc2 = wkc1 + (size_t)384*1152;                  // 384*768  f16
  _Float16* c2w16= wkc2 + (size_t)384*768;                   // 256*256  f16

  dim3 blk(256);

  // 1. h = pad(feature); weight conversions; zero bias
  pad_h_k<<<cdiv(Ntot*OUTF,256), blk, 0, stream>>>(feature, h, h16);
  repack_wext_k<<<cdiv(256*SK,256), blk, 0, stream>>>(W_msg, b_msg, Wext16);
  cvt_k<<<cdiv(768*256/4,256), blk, 0, stream>>>(w_ih, wih16, 768*256);
  cvt_k<<<cdiv(768*256/4,256), blk, 0, stream>>>(w_hh, whh16, 768*256);
  hipMemsetAsync(bias0, 0, 256*4, stream);

  // 2. type-sorted CSR: bucket = dst*4 + type
  zero_int_k<<<cdiv(NB,256), blk, 0, stream>>>(cnt, NB);
  hist_k<<<cdiv(Etot,256), blk, 0, stream>>>(edst, etyp, cnt);
  scan1_k<<<NSB2, 512, 0, stream>>>(cnt, rp2, bsum);
  scan2_k<<<1, blk, 0, stream>>>(bsum);
  scan3_k<<<NSB2, 512, 0, stream>>>(rp2, bsum);
  zero_int_k<<<cdiv(NB,256), blk, 0, stream>>>(cnt, NB);
  fill_k<<<cdiv(Etot,256), blk, 0, stream>>>(edst, etyp, esrc, rp2, cnt, srcv);

  // 3. GGNN steps: type-sorted gather, then a = s @ Wext^T (bias via K-ext)
  for (int s = 0; s < NSTEP; ++s) {
    gather_k<<<Ntot, blk, 0, stream>>>(h16, rp2, srcv, s16);
    hgemm<_Float16,false,false><<<dim3(cdiv(Ntot,128), 2), blk, 0, stream>>>(
        s16, Wext16, bias0, a16, Ntot, 256, SK, SK, 0, 0);
    hgemm<_Float16,false,false><<<dim3(cdiv(Ntot,128), 6), blk, 0, stream>>>(
        a16, wih16, b_ih, gi, Ntot, 768, 256, 256, 0, 0);
    hgemm<_Float16,false,false><<<dim3(cdiv(Ntot,128), 6), blk, 0, stream>>>(
        h16, whh16, b_hh, gh, Ntot, 768, 256, 256, 0, 0);
    gru_gate_k<<<cdiv(Ntot*64,256), blk, 0, stream>>>(gi, gh, h, h16);
  }

  // 4. conv-head weight repacks (conv-phase spare of big)
  repack16_k<<<cdiv(256*256*3,256), blk, 0, stream>>>(conv1_w,  wk1,  256, 256, 3);
  repack16_k<<<cdiv(384*384*3,256), blk, 0, stream>>>(convc1_w, wkc1, 384, 384, 3);
  repack16_k<<<cdiv(384*384*2,256), blk, 0, stream>>>(convc2_w, wkc2, 384, 384, 2);
  cvt_k<<<cdiv(256*256/4,256), blk, 0, stream>>>(conv2_w, c2w16, 256*256);

  // 5. Y head: conv1(K=3) -> pool3 -> conv2(K=1) -> pool2
  hgemm<_Float16,true,true><<<dim3(cdiv(Bg*511,128), 2), blk, 0, stream>>>(
      h16, wk1, conv1_b, y1, Bg*511, 256, 768, 256, 511, NNg);
  maxpool_k<_Float16,_Float16><<<cdiv(Bg*255*256,256), blk, 0, stream>>>(y1, p1, 511, 255, 256, 3);
  hgemm<float,true,false><<<dim3(cdiv(Bg*255,128), 2), blk, 0, stream>>>(
      p1, c2w16, conv2_b, y2, Bg*255, 256, 256, 256, 0, 0);
  maxpool_k<float,float><<<cdiv(Bg*127*256,256), blk, 0, stream>>>(y2, Y2, 255, 127, 256, 2);

  // 6. Z head: cb16=concat(h16,(f16)feature); convc1(K=3) -> pool3 -> convc2(K=2) -> pool2
  build_cb16_k<<<cdiv(Ntot*CATF,256), blk, 0, stream>>>(h16, feature, cb16);
  hgemm<_Float16,true,true><<<dim3(cdiv(Bg*511,128), 3), blk, 0, stream>>>(
      cb16, wkc1, convc1_b, z1, Bg*511, 384, 1152, 384, 511, NNg);
  maxpool_k<_Float16,_Float16><<<cdiv(Bg*255*384,256), blk, 0, stream>>>(z1, pz1, 511, 255, 384, 3);
  hgemm<float,true,true><<<dim3(cdiv(Bg*254,128), 3), blk, 0, stream>>>(
      pz1, wkc2, convc2_b, z2, Bg*254, 384, 768, 384, 254, 255);
  maxpool_k<float,float><<<cdiv(Bg*127*384,256), blk, 0, stream>>>(z2, Z2, 254, 127, 384, 2);

  // 7. head
  head_k<<<Bg, 128, 0, stream>>>(Y2, Z2, mlpy_w, mlpy_b, mlpz_w, mlpz_b, out);
}

// Round 14
// 846.563 us; speedup vs baseline: 1.1108x; 1.0365x over previous
//
#include <hip/hip_runtime.h>

#define Bg    32
#define NNg   513
#define INF   128
#define OUTF  256
#define TT    4
#define NSTEP 4
#define DEGg  16
#define Ntot  (Bg*NNg)        // 16416
#define Etot  (Ntot*DEGg)     // 262656
#define CATF  (OUTF+INF)      // 384
#define SK    1056            // 1024 + 4 cnt + 28 pad
#define NB    (Ntot*TT)       // 65664 buckets (dst*4+type)
#define NSB2  129             // cdiv(NB,512)

typedef _Float16 h8_t __attribute__((ext_vector_type(8)));
typedef _Float16 h4_t __attribute__((ext_vector_type(4)));
typedef float    f4_t __attribute__((ext_vector_type(4)));

// async global->LDS, 16B per lane; LDS dest = wave-uniform base + lane*16 (HW)
#define GLL(gsrc, ldst)                                                        \
  __builtin_amdgcn_global_load_lds(                                            \
      (const __attribute__((address_space(1))) unsigned int*)(gsrc),           \
      (__attribute__((address_space(3))) unsigned int*)(ldst), 16, 0, 0)

// ---------------- elementwise ----------------
__global__ void pad_h_k(const float* __restrict__ feat, float* __restrict__ h,
                        _Float16* __restrict__ h16) {
  int idx = blockIdx.x*256 + threadIdx.x;
  if (idx >= Ntot*OUTF) return;
  int n = idx >> 8, c = idx & 255;
  float v = (c < INF) ? feat[n*INF + c] : 0.f;
  h[idx] = v;
  h16[idx] = (_Float16)v;
}

__global__ void cvt_k(const float* __restrict__ s, _Float16* __restrict__ d, int n) {
  int i = (blockIdx.x*256 + threadIdx.x) * 4;
  if (i >= n) return;
  float4 v = *reinterpret_cast<const float4*>(s + i);
  _Float16 o[4] = {(_Float16)v.x, (_Float16)v.y, (_Float16)v.z, (_Float16)v.w};
  *reinterpret_cast<ushort4*>(d + i) = *reinterpret_cast<ushort4*>(o);
}

// cb16[n][c] = c<256 ? h16[n][c] : (f16)feature[n][c-256]
__global__ void build_cb16_k(const _Float16* __restrict__ h16,
                             const float* __restrict__ feat,
                             _Float16* __restrict__ cb) {
  int idx = blockIdx.x*256 + threadIdx.x;
  if (idx >= Ntot*CATF) return;
  int n = idx / CATF, c = idx % CATF;
  cb[idx] = (c < OUTF) ? h16[n*OUTF + c] : (_Float16)feat[n*INF + (c - OUTF)];
}

__global__ void zero_int_k(int* __restrict__ p, int n) {
  int i = blockIdx.x*256 + threadIdx.x;
  if (i < n) p[i] = 0;
}

// histogram over buckets b = dst*4 + type
__global__ void hist_k(const int* __restrict__ dst, const int* __restrict__ typ,
                       int* __restrict__ cnt) {
  int e = blockIdx.x*256 + threadIdx.x;
  if (e < Etot) atomicAdd(&cnt[dst[e]*TT + typ[e]], 1);
}

// ---- 3-phase parallel exclusive scan of cnt[NB] -> rp2 ----
__global__ void scan1_k(const int* __restrict__ cnt, int* __restrict__ rp2,
                        int* __restrict__ bsum) {
  __shared__ int buf[512];
  int t = threadIdx.x;           // 512 threads
  int i = blockIdx.x*512 + t;
  int v = (i < NB) ? cnt[i] : 0;
  buf[t] = v;
  __syncthreads();
  #pragma unroll
  for (int off = 1; off < 512; off <<= 1) {
    int x = (t >= off) ? buf[t - off] : 0;
    __syncthreads();
    buf[t] += x;
    __syncthreads();
  }
  if (i < NB) rp2[i] = buf[t] - v;       // exclusive within block
  if (t == 511) bsum[blockIdx.x] = buf[511];
}

__global__ void scan2_k(int* __restrict__ bsum) {   // single block; NSB2 <= 256
  __shared__ int buf[256];
  int t = threadIdx.x;
  int v = (t < NSB2) ? bsum[t] : 0;
  buf[t] = v;
  __syncthreads();
  #pragma unroll
  for (int off = 1; off < 256; off <<= 1) {
    int x = (t >= off) ? buf[t - off] : 0;
    __syncthreads();
    buf[t] += x;
    __syncthreads();
  }
  if (t < NSB2) bsum[t] = buf[t] - v;     // exclusive block offsets
}

__global__ void scan3_k(int* __restrict__ rp2, const int* __restrict__ bsum) {
  int i = blockIdx.x*512 + threadIdx.x;
  if (i < NB) rp2[i] += bsum[blockIdx.x];
  if (i == 0) rp2[NB] = Etot;
}

// srcv[rp2[b]+pos] = esrc[e]  (store src node id directly; type implicit in bucket)
__global__ void fill_k(const int* __restrict__ dst, const int* __restrict__ typ,
                       const int* __restrict__ src, const int* __restrict__ rp2,
                       int* __restrict__ cursor, int* __restrict__ srcv) {
  int e = blockIdx.x*256 + threadIdx.x;
  if (e < Etot) {
    int b = dst[e]*TT + typ[e];
    int pos = atomicAdd(&cursor[b], 1);
    srcv[rp2[b] + pos] = src[e];
  }
}

// Type-sorted gather, segment loops hand-unrolled x4 for load ILP.
// s16[n][t*256+c] = sum over type-t in-edges of h16[src][c]; s16[n][1024+t] = count.
__global__ void gather_k(const _Float16* __restrict__ h16, const int* __restrict__ rp2,
                         const int* __restrict__ srcv, _Float16* __restrict__ s16) {
  __shared__ int src_s[128];
  int n = blockIdx.x;
  int c = threadIdx.x;  // 256
  int b0 = rp2[TT*n], e1 = rp2[TT*n+1], e2 = rp2[TT*n+2], e3 = rp2[TT*n+3], e4 = rp2[TT*n+4];
  float a0 = 0.f, a1 = 0.f, a2 = 0.f, a3 = 0.f;
  for (int base = b0; base < e4; base += 128) {
    int m = e4 - base; if (m > 128) m = 128;
    if (c < m) src_s[c] = srcv[base + c];
    __syncthreads();
    int s1 = min(max(e1 - base, 0), m);
    int s2 = min(max(e2 - base, 0), m);
    int s3 = min(max(e3 - base, 0), m);
#define SEG(ACC, ST, EN)                                                   \
    {                                                                      \
      int i = (ST);                                                        \
      for (; i + 4 <= (EN); i += 4) {                                      \
        float v0 = (float)h16[(size_t)src_s[i]  *256 + c];                 \
        float v1 = (float)h16[(size_t)src_s[i+1]*256 + c];                 \
        float v2 = (float)h16[(size_t)src_s[i+2]*256 + c];                 \
        float v3 = (float)h16[(size_t)src_s[i+3]*256 + c];                 \
        ACC += (v0 + v1) + (v2 + v3);                                      \
      }                                                                    \
      for (; i < (EN); ++i) ACC += (float)h16[(size_t)src_s[i]*256 + c];   \
    }
    SEG(a0, 0,  s1)
    SEG(a1, s1, s2)
    SEG(a2, s2, s3)
    SEG(a3, s3, m)
#undef SEG
    __syncthreads();
  }
  size_t b = (size_t)n * SK;
  s16[b + 0*256 + c] = (_Float16)a0;
  s16[b + 1*256 + c] = (_Float16)a1;
  s16[b + 2*256 + c] = (_Float16)a2;
  s16[b + 3*256 + c] = (_Float16)a3;
  if (c < 32) {
    int cv = (c == 0) ? (e1-b0) : (c == 1) ? (e2-e1) : (c == 2) ? (e3-e2) : (c == 3) ? (e4-e3) : 0;
    s16[b + 1024 + c] = (_Float16)(float)cv;
  }
}

// Wext[co][k]: k<1024 -> W_msg[k>>8][co][k&255]; k in [1024,1028) -> b_msg[(k-1024)*256+co]; else 0
__global__ void repack_wext_k(const float* __restrict__ Wmsg, const float* __restrict__ bmsg,
                              _Float16* __restrict__ wext) {
  int idx = blockIdx.x*256 + threadIdx.x;
  if (idx >= 256*SK) return;
  int co = idx / SK, k = idx % SK;
  float v;
  if (k < 1024)      { int t = k >> 8, ci = k & 255; v = Wmsg[((size_t)t*256 + co)*256 + ci]; }
  else if (k < 1028) { v = bmsg[(k - 1024)*256 + co]; }
  else               { v = 0.f; }
  wext[idx] = (_Float16)v;
}

// f16 gi/gh; 4 channels per thread
__global__ void gru_gate_k(const _Float16* __restrict__ gi, const _Float16* __restrict__ gh,
                           float* __restrict__ h, _Float16* __restrict__ h16) {
  int idx = blockIdx.x*256 + threadIdx.x;
  if (idx >= Ntot*64) return;
  int n = idx >> 6, g4 = (idx & 63) * 4;
  const _Float16* gin = gi + (size_t)n*768 + g4;
  const _Float16* ghn = gh + (size_t)n*768 + g4;
  h4_t ir = *reinterpret_cast<const h4_t*>(gin);
  h4_t iz = *reinterpret_cast<const h4_t*>(gin + 256);
  h4_t in_ = *reinterpret_cast<const h4_t*>(gin + 512);
  h4_t hr = *reinterpret_cast<const h4_t*>(ghn);
  h4_t hz = *reinterpret_cast<const h4_t*>(ghn + 256);
  h4_t hn = *reinterpret_cast<const h4_t*>(ghn + 512);
  size_t hb = (size_t)n*256 + g4;
  float4 hv = *reinterpret_cast<const float4*>(h + hb);
  float hvv[4] = {hv.x, hv.y, hv.z, hv.w};
  float ov[4];
  _Float16 ov16[4];
  #pragma unroll
  for (int j = 0; j < 4; ++j) {
    float r  = 1.f / (1.f + expf(-((float)ir[j] + (float)hr[j])));
    float z  = 1.f / (1.f + expf(-((float)iz[j] + (float)hz[j])));
    float nn = tanhf((float)in_[j] + r * (float)hn[j]);
    float o = (1.f - z) * nn + z * hvv[j];
    ov[j] = o;
    ov16[j] = (_Float16)o;
  }
  float4 os = {ov[0], ov[1], ov[2], ov[3]};
  *reinterpret_cast<float4*>(h + hb) = os;
  *reinterpret_cast<ushort4*>(h16 + hb) = *reinterpret_cast<ushort4*>(ov16);
}

template<typename IT, typename OT>
__global__ void maxpool_k(const IT* __restrict__ in, OT* __restrict__ out,
                          int Lin, int Lp, int C, int kwin) {
  int idx = blockIdx.x*256 + threadIdx.x;
  int total = Bg*Lp*C;
  if (idx >= total) return;
  int c = idx % C; int r = idx / C; int p = r % Lp; int b = r / Lp;
  const IT* base = in + ((size_t)(b*Lin + 2*p))*C + c;
  float v = (float)base[0];
  for (int w = 1; w < kwin; ++w) v = fmaxf(v, (float)base[(size_t)w*C]);
  out[idx] = (OT)v;
}

// wk16[co][k][ci] = (f16) w[co][ci][k]
__global__ void repack16_k(const float* __restrict__ w, _Float16* __restrict__ wk,
                           int Cout, int Cin, int K) {
  int idx = blockIdx.x*256 + threadIdx.x;
  int total = Cout*Cin*K;
  if (idx >= total) return;
  int ci = idx % Cin; int r = idx / Cin; int k = r % K; int co = r / K;
  wk[idx] = (_Float16)w[(co*Cin + ci)*K + k];
}

__global__ void head_k(const float* __restrict__ Y2, const float* __restrict__ Z2,
                       const float* __restrict__ wy, const float* __restrict__ by,
                       const float* __restrict__ wz, const float* __restrict__ bz,
                       float* __restrict__ out) {
  int b = blockIdx.x;
  int tid = threadIdx.x;  // 128
  __shared__ float red[128];
  float sum = 0.f;
  for (int p = tid; p < 127; p += 128) {
    const float* yr = Y2 + ((size_t)(b*127 + p))*OUTF;
    const float* zr = Z2 + ((size_t)(b*127 + p))*CATF;
    float yv = by[0], zv = bz[0];
    for (int c = 0; c < OUTF; ++c) yv = fmaf(yr[c], wy[c], yv);
    for (int c = 0; c < CATF; ++c) zv = fmaf(zr[c], wz[c], zv);
    sum += yv * zv;
  }
  red[tid] = sum;
  __syncthreads();
  for (int off = 64; off > 0; off >>= 1) {
    if (tid < off) red[tid] += red[tid + off];
    __syncthreads();
  }
  if (tid == 0) out[b] = 1.f / (1.f + expf(-red[0] / 127.f));
}

// ------------- f16 MFMA GEMM via global_load_lds: C = act(A @ W^T + bias) -------------
// Tile 128x128xK, BK=32, 256 threads = 4 waves (2x2), wave tile 64x64 = 4x4 MFMA frags.
// Staging: global_load_lds 16B/lane into LINEAR LDS [128][32]; bank-conflict-free reads
// via both-sides swizzle: global source col = (slot ^ (row&3))*8, read slot = l4^(l15&3).
// DUAL: blockIdx.z==1 switches to (A2,W2,bias2,C2) — used to batch the gi/gh GEMMs.
template<typename CT, bool RELU, bool MAPPED, bool DUAL>
__global__ __launch_bounds__(256, 3) void hgemm(
    const _Float16* __restrict__ A, const _Float16* __restrict__ W,
    const float* __restrict__ bias, CT* __restrict__ C,
    int M, int Nout, int K, int arstride, int Lout, int NNodes,
    const _Float16* A2, const _Float16* W2, const float* bias2, CT* C2) {
  __shared__ _Float16 As[128*32];
  __shared__ _Float16 Ws[128*32];
  if (DUAL && blockIdx.z == 1) { A = A2; W = W2; bias = bias2; C = C2; }
  int tid = threadIdx.x;
  int lane = tid & 63, wid = tid >> 6;
  int wm = wid >> 1, wn = wid & 1;
  int l15 = lane & 15, l4 = lane >> 4;
  int m0 = blockIdx.x * 128, n0 = blockIdx.y * 128;

  // staging geometry: per wave, lane -> (row-in-16 = lane>>2, slot = lane&3); rounds r0/r1
  int sr  = wid*16 + (lane >> 2);           // tile row, round 0 (round 1 = sr+64; (sr+64)&3==sr&3)
  int scol = ((lane & 3) ^ (sr & 3)) * 8;   // pre-swizzled global f16 column
  int am0r = m0 + sr, am1r = m0 + sr + 64;
  int am0 = (am0r < M) ? am0r : M - 1;      // clamp; OOB rows never stored
  int am1 = (am1r < M) ? am1r : M - 1;
  int an0 = MAPPED ? (am0 / Lout) * NNodes + (am0 % Lout) : am0;
  int an1 = MAPPED ? (am1 / Lout) * NNodes + (am1 % Lout) : am1;
  const _Float16* asrc0 = A + (size_t)an0 * arstride + scol;
  const _Float16* asrc1 = A + (size_t)an1 * arstride + scol;
  const _Float16* wsrc0 = W + (size_t)(n0 + sr) * K + scol;
  const _Float16* wsrc1 = W + (size_t)(n0 + sr + 64) * K + scol;
  _Float16* ald0 = As + (wid*16) * 32;      // wave-uniform LDS bases (HW adds lane*16B)
  _Float16* ald1 = As + (64 + wid*16) * 32;
  _Float16* wld0 = Ws + (wid*16) * 32;
  _Float16* wld1 = Ws + (64 + wid*16) * 32;

  int sl = l4 ^ (l15 & 3);                  // read-side swizzle slot
  f4_t acc[4][4] = {};

  for (int k0 = 0; k0 < K; k0 += 32) {
    if (k0) __syncthreads();
    GLL(asrc0 + k0, ald0);
    GLL(asrc1 + k0, ald1);
    GLL(wsrc0 + k0, wld0);
    GLL(wsrc1 + k0, wld1);
    __syncthreads();   // drains vmcnt (incl. global_load_lds) before reads

    h8_t af[4], bf[4];
    #pragma unroll
    for (int fm = 0; fm < 4; ++fm)
      af[fm] = *reinterpret_cast<const h8_t*>(As + (wm*64 + fm*16 + l15)*32 + sl*8);
    #pragma unroll
    for (int fn = 0; fn < 4; ++fn)
      bf[fn] = *reinterpret_cast<const h8_t*>(Ws + (wn*64 + fn*16 + l15)*32 + sl*8);
    #pragma unroll
    for (int fm = 0; fm < 4; ++fm)
      #pragma unroll
      for (int fn = 0; fn < 4; ++fn)
        acc[fm][fn] = __builtin_amdgcn_mfma_f32_16x16x32_f16(af[fm], bf[fn], acc[fm][fn], 0, 0, 0);
  }

  // epilogue: D row = (lane>>4)*4 + reg, col = lane&15  (verified C/D layout)
  #pragma unroll
  for (int fn = 0; fn < 4; ++fn) {
    int col = n0 + wn*64 + fn*16 + l15;
    float bv = bias[col];
    #pragma unroll
    for (int fm = 0; fm < 4; ++fm) {
      #pragma unroll
      for (int i = 0; i < 4; ++i) {
        int m = m0 + wm*64 + fm*16 + l4*4 + i;
        if (m >= M) continue;
        float v = acc[fm][fn][i] + bv;
        if (RELU) v = fmaxf(v, 0.f);
        C[(size_t)m * Nout + col] = (CT)v;
      }
    }
  }
}

static inline int cdiv(int x, int y) { return (x + y - 1) / y; }

extern "C" void kernel_launch(void* const* d_in, const int* in_sizes, int n_in,
                              void* d_out, int out_size, void* d_ws, size_t ws_size,
                              hipStream_t stream) {
  const float* feature  = (const float*)d_in[0];
  const float* W_msg    = (const float*)d_in[1];   // [4,256,256]
  const float* b_msg    = (const float*)d_in[2];   // [1024]
  const float* w_ih     = (const float*)d_in[3];
  const float* w_hh     = (const float*)d_in[4];
  const float* b_ih     = (const float*)d_in[5];
  const float* b_hh     = (const float*)d_in[6];
  const float* conv1_w  = (const float*)d_in[7];
  const float* conv1_b  = (const float*)d_in[8];
  const float* conv2_w  = (const float*)d_in[9];   // [256,256,1]
  const float* conv2_b  = (const float*)d_in[10];
  const float* convc1_w = (const float*)d_in[11];
  const float* convc1_b = (const float*)d_in[12];
  const float* convc2_w = (const float*)d_in[13];
  const float* convc2_b = (const float*)d_in[14];
  const float* mlpy_w   = (const float*)d_in[15];
  const float* mlpy_b   = (const float*)d_in[16];
  const float* mlpz_w   = (const float*)d_in[17];
  const float* mlpz_b   = (const float*)d_in[18];
  const int*   esrc     = (const int*)d_in[19];
  const int*   edst     = (const int*)d_in[20];
  const int*   etyp     = (const int*)d_in[21];
  float* out = (float*)d_out;

  // ---- workspace layout (bytes); peak ~128 MB ----
  char* base = (char*)d_ws;
  size_t off = 0;
  auto alloc = [&](size_t bytes) { void* p = base + off; off = (off + bytes + 255) & ~(size_t)255; return p; };
  float*    h      = (float*)   alloc((size_t)Ntot*OUTF*4);    // 16.8 MB
  _Float16* h16    = (_Float16*)alloc((size_t)Ntot*OUTF*2);    //  8.4 MB
  _Float16* Wext16 = (_Float16*)alloc((size_t)256*SK*2);       //  0.54 MB
  _Float16* wih16  = (_Float16*)alloc((size_t)768*256*2);
  _Float16* whh16  = (_Float16*)alloc((size_t)768*256*2);
  float*    bias0  = (float*)   alloc(256*4);                  // zeros
  int* rp2    = (int*)alloc((NB+1)*4);                         // bucket rowptr
  int* cnt    = (int*)alloc(NB*4);
  int* bsum   = (int*)alloc(NSB2*4);
  int* srcv   = (int*)alloc((size_t)Etot*4);                   // type-sorted src ids
  char* big   = (char*)alloc((size_t)Ntot*1536*4);             // 100.9 MB shared region
  // GGNN phase views of big (f16 gi/gh):
  _Float16* gi  = (_Float16*)big;
  _Float16* gh  = gi + (size_t)Ntot*768;
  _Float16* s16 = (_Float16*)(big + (size_t)Ntot*768*4);
  _Float16* a16 = s16 + (size_t)Ntot*SK;
  // conv phase views of big (GGNN scratch dead; ~77 MB <= 100.9MB)
  float*    Y2   = (float*)big;                              // 32*127*256 f32
  float*    Z2   = Y2 + (size_t)Bg*127*OUTF;                 // 32*127*384 f32
  _Float16* y1   = (_Float16*)(Z2 + (size_t)Bg*127*CATF);    // 32*511*256 f16
  float*    y2   = (float*)(y1 + (size_t)Bg*511*OUTF);       // 32*255*256 f32
  _Float16* p1   = (_Float16*)(y2 + (size_t)Bg*255*OUTF);    // 32*255*256 f16
  _Float16* cb16 = p1 + (size_t)Bg*255*OUTF;                 // 16416*384 f16
  _Float16* z1   = cb16 + (size_t)Ntot*CATF;                 // 32*511*384 f16
  float*    z2   = (float*)(z1 + (size_t)Bg*511*CATF);       // 32*254*384 f32
  _Float16* pz1  = (_Float16*)(z2 + (size_t)Bg*254*CATF);    // 32*255*384 f16
  _Float16* wk1  = pz1 + (size_t)Bg*255*CATF;                // 256*768  f16 (conv-phase only)
  _Float16* wkc1 = wk1 + (size_t)256*768;                    // 384*1152 f16
  _Float16* wkc2 = wkc1 + (size_t)384*1152;                  // 384*768  f16
  _Float16* c2w16= wkc2 + (size_t)384*768;                   // 256*256  f16

  dim3 blk(256);

  // 1. h = pad(feature); weight conversions; zero bias
  pad_h_k<<<cdiv(Ntot*OUTF,256), blk, 0, stream>>>(feature, h, h16);
  repack_wext_k<<<cdiv(256*SK,256), blk, 0, stream>>>(W_msg, b_msg, Wext16);
  cvt_k<<<cdiv(768*256/4,256), blk, 0, stream>>>(w_ih, wih16, 768*256);
  cvt_k<<<cdiv(768*256/4,256), blk, 0, stream>>>(w_hh, whh16, 768*256);
  hipMemsetAsync(bias0, 0, 256*4, stream);

  // 2. type-sorted CSR: bucket = dst*4 + type
  zero_int_k<<<cdiv(NB,256), blk, 0, stream>>>(cnt, NB);
  hist_k<<<cdiv(Etot,256), blk, 0, stream>>>(edst, etyp, cnt);
  scan1_k<<<NSB2, 512, 0, stream>>>(cnt, rp2, bsum);
  scan2_k<<<1, blk, 0, stream>>>(bsum);
  scan3_k<<<NSB2, 512, 0, stream>>>(rp2, bsum);
  zero_int_k<<<cdiv(NB,256), blk, 0, stream>>>(cnt, NB);
  fill_k<<<cdiv(Etot,256), blk, 0, stream>>>(edst, etyp, esrc, rp2, cnt, srcv);

  // 3. GGNN steps: gather -> a-GEMM -> (gi|gh dual GEMM) -> gates
  for (int s = 0; s < NSTEP; ++s) {
    gather_k<<<Ntot, blk, 0, stream>>>(h16, rp2, srcv, s16);
    hgemm<_Float16,false,false,false><<<dim3(cdiv(Ntot,128), 2), blk, 0, stream>>>(
        s16, Wext16, bias0, a16, Ntot, 256, SK, SK, 0, 0,
        nullptr, nullptr, nullptr, nullptr);
    hgemm<_Float16,false,false,true><<<dim3(cdiv(Ntot,128), 6, 2), blk, 0, stream>>>(
        a16, wih16, b_ih, gi, Ntot, 768, 256, 256, 0, 0,
        h16, whh16, b_hh, gh);
    gru_gate_k<<<cdiv(Ntot*64,256), blk, 0, stream>>>(gi, gh, h, h16);
  }

  // 4. conv-head weight repacks (conv-phase spare of big)
  repack16_k<<<cdiv(256*256*3,256), blk, 0, stream>>>(conv1_w,  wk1,  256, 256, 3);
  repack16_k<<<cdiv(384*384*3,256), blk, 0, stream>>>(convc1_w, wkc1, 384, 384, 3);
  repack16_k<<<cdiv(384*384*2,256), blk, 0, stream>>>(convc2_w, wkc2, 384, 384, 2);
  cvt_k<<<cdiv(256*256/4,256), blk, 0, stream>>>(conv2_w, c2w16, 256*256);

  // 5. Y head: conv1(K=3) -> pool3 -> conv2(K=1) -> pool2
  hgemm<_Float16,true,true,false><<<dim3(cdiv(Bg*511,128), 2), blk, 0, stream>>>(
      h16, wk1, conv1_b, y1, Bg*511, 256, 768, 256, 511, NNg,
      nullptr, nullptr, nullptr, nullptr);
  maxpool_k<_Float16,_Float16><<<cdiv(Bg*255*256,256), blk, 0, stream>>>(y1, p1, 511, 255, 256, 3);
  hgemm<float,true,false,false><<<dim3(cdiv(Bg*255,128), 2), blk, 0, stream>>>(
      p1, c2w16, conv2_b, y2, Bg*255, 256, 256, 256, 0, 0,
      nullptr, nullptr, nullptr, nullptr);
  maxpool_k<float,float><<<cdiv(Bg*127*256,256), blk, 0, stream>>>(y2, Y2, 255, 127, 256, 2);

  // 6. Z head: cb16=concat(h16,(f16)feature); convc1(K=3) -> pool3 -> convc2(K=2) -> pool2
  build_cb16_k<<<cdiv(Ntot*CATF,256), blk, 0, stream>>>(h16, feature, cb16);
  hgemm<_Float16,true,true,false><<<dim3(cdiv(Bg*511,128), 3), blk, 0, stream>>>(
      cb16, wkc1, convc1_b, z1, Bg*511, 384, 1152, 384, 511, NNg,
      nullptr, nullptr, nullptr, nullptr);
  maxpool_k<_Float16,_Float16><<<cdiv(Bg*255*384,256), blk, 0, stream>>>(z1, pz1, 511, 255, 384, 3);
  hgemm<float,true,true,false><<<dim3(cdiv(Bg*254,128), 3), blk, 0, stream>>>(
      pz1, wkc2, convc2_b, z2, Bg*254, 384, 768, 384, 254, 255,
      nullptr, nullptr, nullptr, nullptr);
  maxpool_k<float,float><<<cdiv(Bg*127*384,256), blk, 0, stream>>>(z2, Z2, 254, 127, 384, 2);

  // 7. head
  head_k<<<Bg, 128, 0, stream>>>(Y2, Z2, mlpy_w, mlpy_b, mlpz_w, mlpz_b, out);
}

// Round 15
// 828.410 us; speedup vs baseline: 1.1351x; 1.0219x over previous
//
#include <hip/hip_runtime.h>

#define Bg    32
#define NNg   513
#define INF   128
#define OUTF  256
#define TT    4
#define NSTEP 4
#define DEGg  16
#define Ntot  (Bg*NNg)        // 16416
#define Etot  (Ntot*DEGg)     // 262656
#define CATF  (OUTF+INF)      // 384
#define SK    1056            // 1024 + 4 cnt + 28 pad
#define NB    (Ntot*TT)       // 65664 buckets (dst*4+type)
#define NSB2  129             // cdiv(NB,512)

typedef _Float16 h8_t __attribute__((ext_vector_type(8)));
typedef _Float16 h4_t __attribute__((ext_vector_type(4)));
typedef float    f4_t __attribute__((ext_vector_type(4)));

// async global->LDS, 16B per lane; LDS dest = wave-uniform base + lane*16 (HW)
#define GLL(gsrc, ldst)                                                        \
  __builtin_amdgcn_global_load_lds(                                            \
      (const __attribute__((address_space(1))) unsigned int*)(gsrc),           \
      (__attribute__((address_space(3))) unsigned int*)(ldst), 16, 0, 0)

// ---------------- elementwise ----------------
__global__ void pad_h_k(const float* __restrict__ feat, float* __restrict__ h,
                        _Float16* __restrict__ h16) {
  int idx = blockIdx.x*256 + threadIdx.x;
  if (idx >= Ntot*OUTF) return;
  int n = idx >> 8, c = idx & 255;
  float v = (c < INF) ? feat[n*INF + c] : 0.f;
  h[idx] = v;
  h16[idx] = (_Float16)v;
}

__global__ void cvt_k(const float* __restrict__ s, _Float16* __restrict__ d, int n) {
  int i = (blockIdx.x*256 + threadIdx.x) * 4;
  if (i >= n) return;
  float4 v = *reinterpret_cast<const float4*>(s + i);
  _Float16 o[4] = {(_Float16)v.x, (_Float16)v.y, (_Float16)v.z, (_Float16)v.w};
  *reinterpret_cast<ushort4*>(d + i) = *reinterpret_cast<ushort4*>(o);
}

// cb16[n][c] = c<256 ? h16[n][c] : (f16)feature[n][c-256]
__global__ void build_cb16_k(const _Float16* __restrict__ h16,
                             const float* __restrict__ feat,
                             _Float16* __restrict__ cb) {
  int idx = blockIdx.x*256 + threadIdx.x;
  if (idx >= Ntot*CATF) return;
  int n = idx / CATF, c = idx % CATF;
  cb[idx] = (c < OUTF) ? h16[n*OUTF + c] : (_Float16)feat[n*INF + (c - OUTF)];
}

__global__ void zero_int_k(int* __restrict__ p, int n) {
  int i = blockIdx.x*256 + threadIdx.x;
  if (i < n) p[i] = 0;
}

// histogram over buckets b = dst*4 + type
__global__ void hist_k(const int* __restrict__ dst, const int* __restrict__ typ,
                       int* __restrict__ cnt) {
  int e = blockIdx.x*256 + threadIdx.x;
  if (e < Etot) atomicAdd(&cnt[dst[e]*TT + typ[e]], 1);
}

// ---- 3-phase parallel exclusive scan of cnt[NB] -> rp2 ----
__global__ void scan1_k(const int* __restrict__ cnt, int* __restrict__ rp2,
                        int* __restrict__ bsum) {
  __shared__ int buf[512];
  int t = threadIdx.x;           // 512 threads
  int i = blockIdx.x*512 + t;
  int v = (i < NB) ? cnt[i] : 0;
  buf[t] = v;
  __syncthreads();
  #pragma unroll
  for (int off = 1; off < 512; off <<= 1) {
    int x = (t >= off) ? buf[t - off] : 0;
    __syncthreads();
    buf[t] += x;
    __syncthreads();
  }
  if (i < NB) rp2[i] = buf[t] - v;       // exclusive within block
  if (t == 511) bsum[blockIdx.x] = buf[511];
}

__global__ void scan2_k(int* __restrict__ bsum) {   // single block; NSB2 <= 256
  __shared__ int buf[256];
  int t = threadIdx.x;
  int v = (t < NSB2) ? bsum[t] : 0;
  buf[t] = v;
  __syncthreads();
  #pragma unroll
  for (int off = 1; off < 256; off <<= 1) {
    int x = (t >= off) ? buf[t - off] : 0;
    __syncthreads();
    buf[t] += x;
    __syncthreads();
  }
  if (t < NSB2) bsum[t] = buf[t] - v;     // exclusive block offsets
}

__global__ void scan3_k(int* __restrict__ rp2, const int* __restrict__ bsum) {
  int i = blockIdx.x*512 + threadIdx.x;
  if (i < NB) rp2[i] += bsum[blockIdx.x];
  if (i == 0) rp2[NB] = Etot;
}

// srcv[rp2[b]+pos] = esrc[e]  (store src node id directly; type implicit in bucket)
__global__ void fill_k(const int* __restrict__ dst, const int* __restrict__ typ,
                       const int* __restrict__ src, const int* __restrict__ rp2,
                       int* __restrict__ cursor, int* __restrict__ srcv) {
  int e = blockIdx.x*256 + threadIdx.x;
  if (e < Etot) {
    int b = dst[e]*TT + typ[e];
    int pos = atomicAdd(&cursor[b], 1);
    srcv[rp2[b] + pos] = src[e];
  }
}

// Type-sorted gather, segment loops hand-unrolled x4 for load ILP.
// s16[n][t*256+c] = sum over type-t in-edges of h16[src][c]; s16[n][1024+t] = count.
__global__ void gather_k(const _Float16* __restrict__ h16, const int* __restrict__ rp2,
                         const int* __restrict__ srcv, _Float16* __restrict__ s16) {
  __shared__ int src_s[128];
  int n = blockIdx.x;
  int c = threadIdx.x;  // 256
  int b0 = rp2[TT*n], e1 = rp2[TT*n+1], e2 = rp2[TT*n+2], e3 = rp2[TT*n+3], e4 = rp2[TT*n+4];
  float a0 = 0.f, a1 = 0.f, a2 = 0.f, a3 = 0.f;
  for (int base = b0; base < e4; base += 128) {
    int m = e4 - base; if (m > 128) m = 128;
    if (c < m) src_s[c] = srcv[base + c];
    __syncthreads();
    int s1 = min(max(e1 - base, 0), m);
    int s2 = min(max(e2 - base, 0), m);
    int s3 = min(max(e3 - base, 0), m);
#define SEG(ACC, ST, EN)                                                   \
    {                                                                      \
      int i = (ST);                                                        \
      for (; i + 4 <= (EN); i += 4) {                                      \
        float v0 = (float)h16[(size_t)src_s[i]  *256 + c];                 \
        float v1 = (float)h16[(size_t)src_s[i+1]*256 + c];                 \
        float v2 = (float)h16[(size_t)src_s[i+2]*256 + c];                 \
        float v3 = (float)h16[(size_t)src_s[i+3]*256 + c];                 \
        ACC += (v0 + v1) + (v2 + v3);                                      \
      }                                                                    \
      for (; i < (EN); ++i) ACC += (float)h16[(size_t)src_s[i]*256 + c];   \
    }
    SEG(a0, 0,  s1)
    SEG(a1, s1, s2)
    SEG(a2, s2, s3)
    SEG(a3, s3, m)
#undef SEG
    __syncthreads();
  }
  size_t b = (size_t)n * SK;
  s16[b + 0*256 + c] = (_Float16)a0;
  s16[b + 1*256 + c] = (_Float16)a1;
  s16[b + 2*256 + c] = (_Float16)a2;
  s16[b + 3*256 + c] = (_Float16)a3;
  if (c < 32) {
    int cv = (c == 0) ? (e1-b0) : (c == 1) ? (e2-e1) : (c == 2) ? (e3-e2) : (c == 3) ? (e4-e3) : 0;
    s16[b + 1024 + c] = (_Float16)(float)cv;
  }
}

// Wext[co][k]: k<1024 -> W_msg[k>>8][co][k&255]; k in [1024,1028) -> b_msg[(k-1024)*256+co]; else 0
__global__ void repack_wext_k(const float* __restrict__ Wmsg, const float* __restrict__ bmsg,
                              _Float16* __restrict__ wext) {
  int idx = blockIdx.x*256 + threadIdx.x;
  if (idx >= 256*SK) return;
  int co = idx / SK, k = idx % SK;
  float v;
  if (k < 1024)      { int t = k >> 8, ci = k & 255; v = Wmsg[((size_t)t*256 + co)*256 + ci]; }
  else if (k < 1028) { v = bmsg[(k - 1024)*256 + co]; }
  else               { v = 0.f; }
  wext[idx] = (_Float16)v;
}

// f16 gi/gh; 4 channels per thread
__global__ void gru_gate_k(const _Float16* __restrict__ gi, const _Float16* __restrict__ gh,
                           float* __restrict__ h, _Float16* __restrict__ h16) {
  int idx = blockIdx.x*256 + threadIdx.x;
  if (idx >= Ntot*64) return;
  int n = idx >> 6, g4 = (idx & 63) * 4;
  const _Float16* gin = gi + (size_t)n*768 + g4;
  const _Float16* ghn = gh + (size_t)n*768 + g4;
  h4_t ir = *reinterpret_cast<const h4_t*>(gin);
  h4_t iz = *reinterpret_cast<const h4_t*>(gin + 256);
  h4_t in_ = *reinterpret_cast<const h4_t*>(gin + 512);
  h4_t hr = *reinterpret_cast<const h4_t*>(ghn);
  h4_t hz = *reinterpret_cast<const h4_t*>(ghn + 256);
  h4_t hn = *reinterpret_cast<const h4_t*>(ghn + 512);
  size_t hb = (size_t)n*256 + g4;
  float4 hv = *reinterpret_cast<const float4*>(h + hb);
  float hvv[4] = {hv.x, hv.y, hv.z, hv.w};
  float ov[4];
  _Float16 ov16[4];
  #pragma unroll
  for (int j = 0; j < 4; ++j) {
    float r  = 1.f / (1.f + expf(-((float)ir[j] + (float)hr[j])));
    float z  = 1.f / (1.f + expf(-((float)iz[j] + (float)hz[j])));
    float nn = tanhf((float)in_[j] + r * (float)hn[j]);
    float o = (1.f - z) * nn + z * hvv[j];
    ov[j] = o;
    ov16[j] = (_Float16)o;
  }
  float4 os = {ov[0], ov[1], ov[2], ov[3]};
  *reinterpret_cast<float4*>(h + hb) = os;
  *reinterpret_cast<ushort4*>(h16 + hb) = *reinterpret_cast<ushort4*>(ov16);
}

template<typename IT, typename OT>
__global__ void maxpool_k(const IT* __restrict__ in, OT* __restrict__ out,
                          int Lin, int Lp, int C, int kwin) {
  int idx = blockIdx.x*256 + threadIdx.x;
  int total = Bg*Lp*C;
  if (idx >= total) return;
  int c = idx % C; int r = idx / C; int p = r % Lp; int b = r / Lp;
  const IT* base = in + ((size_t)(b*Lin + 2*p))*C + c;
  float v = (float)base[0];
  for (int w = 1; w < kwin; ++w) v = fmaxf(v, (float)base[(size_t)w*C]);
  out[idx] = (OT)v;
}

// wk16[co][k][ci] = (f16) w[co][ci][k]
__global__ void repack16_k(const float* __restrict__ w, _Float16* __restrict__ wk,
                           int Cout, int Cin, int K) {
  int idx = blockIdx.x*256 + threadIdx.x;
  int total = Cout*Cin*K;
  if (idx >= total) return;
  int ci = idx % Cin; int r = idx / Cin; int k = r % K; int co = r / K;
  wk[idx] = (_Float16)w[(co*Cin + ci)*K + k];
}

__global__ void head_k(const float* __restrict__ Y2, const float* __restrict__ Z2,
                       const float* __restrict__ wy, const float* __restrict__ by,
                       const float* __restrict__ wz, const float* __restrict__ bz,
                       float* __restrict__ out) {
  int b = blockIdx.x;
  int tid = threadIdx.x;  // 128
  __shared__ float red[128];
  float sum = 0.f;
  for (int p = tid; p < 127; p += 128) {
    const float* yr = Y2 + ((size_t)(b*127 + p))*OUTF;
    const float* zr = Z2 + ((size_t)(b*127 + p))*CATF;
    float yv = by[0], zv = bz[0];
    for (int c = 0; c < OUTF; ++c) yv = fmaf(yr[c], wy[c], yv);
    for (int c = 0; c < CATF; ++c) zv = fmaf(zr[c], wz[c], zv);
    sum += yv * zv;
  }
  red[tid] = sum;
  __syncthreads();
  for (int off = 64; off > 0; off >>= 1) {
    if (tid < off) red[tid] += red[tid + off];
    __syncthreads();
  }
  if (tid == 0) out[b] = 1.f / (1.f + expf(-red[0] / 127.f));
}

// ------- f16 MFMA GEMM, double-buffered global_load_lds: C = act(A @ W^T + bias) -------
// Tile 128x128xK, BK=32, 256 threads = 4 waves (2x2), wave tile 64x64 = 4x4 MFMA frags.
// 2-phase schedule: prefetch tile t+1 issued right AFTER the barrier, before consuming
// tile t — __syncthreads' implicit vmcnt(0) then drains exactly the needed loads.
// Bank swizzle (both-sides involution): source col = (slot ^ ((row>>1)&3))*8,
// read slot sl = l4 ^ ((l15>>1)&3)  -> 2-way aliasing per 16-lane phase (free).
// DUAL: blockIdx.z==1 switches to (A2,W2,bias2,C2) — batches the gi/gh GEMMs.
template<typename CT, bool RELU, bool MAPPED, bool DUAL>
__global__ __launch_bounds__(256, 4) void hgemm(
    const _Float16* __restrict__ A, const _Float16* __restrict__ W,
    const float* __restrict__ bias, CT* __restrict__ C,
    int M, int Nout, int K, int arstride, int Lout, int NNodes,
    const _Float16* A2, const _Float16* W2, const float* bias2, CT* C2) {
  __shared__ _Float16 As[2][128*32];
  __shared__ _Float16 Ws[2][128*32];
  if (DUAL && blockIdx.z == 1) { A = A2; W = W2; bias = bias2; C = C2; }
  int tid = threadIdx.x;
  int lane = tid & 63, wid = tid >> 6;
  int wm = wid >> 1, wn = wid & 1;
  int l15 = lane & 15, l4 = lane >> 4;
  int m0 = blockIdx.x * 128, n0 = blockIdx.y * 128;

  // staging geometry: lane -> (row-in-16 = lane>>2, slot = lane&3); rounds r0/r1 (+64 rows)
  int sr  = wid*16 + (lane >> 2);
  int scol = ((lane & 3) ^ ((sr >> 1) & 3)) * 8;   // pre-swizzled global f16 column
  int am0r = m0 + sr, am1r = m0 + sr + 64;
  int am0 = (am0r < M) ? am0r : M - 1;             // clamp; OOB rows never stored
  int am1 = (am1r < M) ? am1r : M - 1;
  int an0 = MAPPED ? (am0 / Lout) * NNodes + (am0 % Lout) : am0;
  int an1 = MAPPED ? (am1 / Lout) * NNodes + (am1 % Lout) : am1;
  const _Float16* asrc0 = A + (size_t)an0 * arstride + scol;
  const _Float16* asrc1 = A + (size_t)an1 * arstride + scol;
  const _Float16* wsrc0 = W + (size_t)(n0 + sr) * K + scol;
  const _Float16* wsrc1 = W + (size_t)(n0 + sr + 64) * K + scol;
  int ld0 = (wid*16) * 32;        // wave-uniform LDS element offsets (HW adds lane*16B)
  int ld1 = (64 + wid*16) * 32;

  int sl = l4 ^ ((l15 >> 1) & 3);                  // read-side swizzle slot
  f4_t acc[4][4] = {};
  int T = K >> 5;

  // prologue: tile 0 -> buf 0
  GLL(asrc0, &As[0][ld0]);
  GLL(asrc1, &As[0][ld1]);
  GLL(wsrc0, &Ws[0][ld0]);
  GLL(wsrc1, &Ws[0][ld1]);

  for (int t = 0; t < T; ++t) {
    __syncthreads();               // vmcnt(0): cur tile landed (only cur loads in flight)
    int cur = t & 1;
    if (t + 1 < T) {               // prefetch next tile into the other buffer
      int k1 = (t + 1) << 5;
      GLL(asrc0 + k1, &As[cur ^ 1][ld0]);
      GLL(asrc1 + k1, &As[cur ^ 1][ld1]);
      GLL(wsrc0 + k1, &Ws[cur ^ 1][ld0]);
      GLL(wsrc1 + k1, &Ws[cur ^ 1][ld1]);
    }
    h8_t af[4], bf[4];
    #pragma unroll
    for (int fm = 0; fm < 4; ++fm)
      af[fm] = *reinterpret_cast<const h8_t*>(&As[cur][(wm*64 + fm*16 + l15)*32 + sl*8]);
    #pragma unroll
    for (int fn = 0; fn < 4; ++fn)
      bf[fn] = *reinterpret_cast<const h8_t*>(&Ws[cur][(wn*64 + fn*16 + l15)*32 + sl*8]);
    #pragma unroll
    for (int fm = 0; fm < 4; ++fm)
      #pragma unroll
      for (int fn = 0; fn < 4; ++fn)
        acc[fm][fn] = __builtin_amdgcn_mfma_f32_16x16x32_f16(af[fm], bf[fn], acc[fm][fn], 0, 0, 0);
  }

  // epilogue: D row = (lane>>4)*4 + reg, col = lane&15  (verified C/D layout)
  #pragma unroll
  for (int fn = 0; fn < 4; ++fn) {
    int col = n0 + wn*64 + fn*16 + l15;
    float bv = bias[col];
    #pragma unroll
    for (int fm = 0; fm < 4; ++fm) {
      #pragma unroll
      for (int i = 0; i < 4; ++i) {
        int m = m0 + wm*64 + fm*16 + l4*4 + i;
        if (m >= M) continue;
        float v = acc[fm][fn][i] + bv;
        if (RELU) v = fmaxf(v, 0.f);
        C[(size_t)m * Nout + col] = (CT)v;
      }
    }
  }
}

static inline int cdiv(int x, int y) { return (x + y - 1) / y; }

extern "C" void kernel_launch(void* const* d_in, const int* in_sizes, int n_in,
                              void* d_out, int out_size, void* d_ws, size_t ws_size,
                              hipStream_t stream) {
  const float* feature  = (const float*)d_in[0];
  const float* W_msg    = (const float*)d_in[1];   // [4,256,256]
  const float* b_msg    = (const float*)d_in[2];   // [1024]
  const float* w_ih     = (const float*)d_in[3];
  const float* w_hh     = (const float*)d_in[4];
  const float* b_ih     = (const float*)d_in[5];
  const float* b_hh     = (const float*)d_in[6];
  const float* conv1_w  = (const float*)d_in[7];
  const float* conv1_b  = (const float*)d_in[8];
  const float* conv2_w  = (const float*)d_in[9];   // [256,256,1]
  const float* conv2_b  = (const float*)d_in[10];
  const float* convc1_w = (const float*)d_in[11];
  const float* convc1_b = (const float*)d_in[12];
  const float* convc2_w = (const float*)d_in[13];
  const float* convc2_b = (const float*)d_in[14];
  const float* mlpy_w   = (const float*)d_in[15];
  const float* mlpy_b   = (const float*)d_in[16];
  const float* mlpz_w   = (const float*)d_in[17];
  const float* mlpz_b   = (const float*)d_in[18];
  const int*   esrc     = (const int*)d_in[19];
  const int*   edst     = (const int*)d_in[20];
  const int*   etyp     = (const int*)d_in[21];
  float* out = (float*)d_out;

  // ---- workspace layout (bytes); peak ~128 MB ----
  char* base = (char*)d_ws;
  size_t off = 0;
  auto alloc = [&](size_t bytes) { void* p = base + off; off = (off + bytes + 255) & ~(size_t)255; return p; };
  float*    h      = (float*)   alloc((size_t)Ntot*OUTF*4);    // 16.8 MB
  _Float16* h16    = (_Float16*)alloc((size_t)Ntot*OUTF*2);    //  8.4 MB
  _Float16* Wext16 = (_Float16*)alloc((size_t)256*SK*2);       //  0.54 MB
  _Float16* wih16  = (_Float16*)alloc((size_t)768*256*2);
  _Float16* whh16  = (_Float16*)alloc((size_t)768*256*2);
  float*    bias0  = (float*)   alloc(256*4);                  // zeros
  int* rp2    = (int*)alloc((NB+1)*4);                         // bucket rowptr
  int* cnt    = (int*)alloc(NB*4);
  int* bsum   = (int*)alloc(NSB2*4);
  int* srcv   = (int*)alloc((size_t)Etot*4);                   // type-sorted src ids
  char* big   = (char*)alloc((size_t)Ntot*1536*4);             // 100.9 MB shared region
  // GGNN phase views of big (f16 gi/gh):
  _Float16* gi  = (_Float16*)big;
  _Float16* gh  = gi + (size_t)Ntot*768;
  _Float16* s16 = (_Float16*)(big + (size_t)Ntot*768*4);
  _Float16* a16 = s16 + (size_t)Ntot*SK;
  // conv phase views of big (GGNN scratch dead; ~77 MB <= 100.9MB)
  float*    Y2   = (float*)big;                              // 32*127*256 f32
  float*    Z2   = Y2 + (size_t)Bg*127*OUTF;                 // 32*127*384 f32
  _Float16* y1   = (_Float16*)(Z2 + (size_t)Bg*127*CATF);    // 32*511*256 f16
  float*    y2   = (float*)(y1 + (size_t)Bg*511*OUTF);       // 32*255*256 f32
  _Float16* p1   = (_Float16*)(y2 + (size_t)Bg*255*OUTF);    // 32*255*256 f16
  _Float16* cb16 = p1 + (size_t)Bg*255*OUTF;                 // 16416*384 f16
  _Float16* z1   = cb16 + (size_t)Ntot*CATF;                 // 32*511*384 f16
  float*    z2   = (float*)(z1 + (size_t)Bg*511*CATF);       // 32*254*384 f32
  _Float16* pz1  = (_Float16*)(z2 + (size_t)Bg*254*CATF);    // 32*255*384 f16
  _Float16* wk1  = pz1 + (size_t)Bg*255*CATF;                // 256*768  f16 (conv-phase only)
  _Float16* wkc1 = wk1 + (size_t)256*768;                    // 384*1152 f16
  _Float16* wkc2 = wkc1 + (size_t)384*1152;                  // 384*768  f16
  _Float16* c2w16= wkc2 + (size_t)384*768;                   // 256*256  f16

  dim3 blk(256);

  // 1. h = pad(feature); weight conversions; zero bias
  pad_h_k<<<cdiv(Ntot*OUTF,256), blk, 0, stream>>>(feature, h, h16);
  repack_wext_k<<<cdiv(256*SK,256), blk, 0, stream>>>(W_msg, b_msg, Wext16);
  cvt_k<<<cdiv(768*256/4,256), blk, 0, stream>>>(w_ih, wih16, 768*256);
  cvt_k<<<cdiv(768*256/4,256), blk, 0, stream>>>(w_hh, whh16, 768*256);
  hipMemsetAsync(bias0, 0, 256*4, stream);

  // 2. type-sorted CSR: bucket = dst*4 + type
  zero_int_k<<<cdiv(NB,256), blk, 0, stream>>>(cnt, NB);
  hist_k<<<cdiv(Etot,256), blk, 0, stream>>>(edst, etyp, cnt);
  scan1_k<<<NSB2, 512, 0, stream>>>(cnt, rp2, bsum);
  scan2_k<<<1, blk, 0, stream>>>(bsum);
  scan3_k<<<NSB2, 512, 0, stream>>>(rp2, bsum);
  zero_int_k<<<cdiv(NB,256), blk, 0, stream>>>(cnt, NB);
  fill_k<<<cdiv(Etot,256), blk, 0, stream>>>(edst, etyp, esrc, rp2, cnt, srcv);

  // 3. GGNN steps: gather -> a-GEMM -> (gi|gh dual GEMM) -> gates
  for (int s = 0; s < NSTEP; ++s) {
    gather_k<<<Ntot, blk, 0, stream>>>(h16, rp2, srcv, s16);
    hgemm<_Float16,false,false,false><<<dim3(cdiv(Ntot,128), 2), blk, 0, stream>>>(
        s16, Wext16, bias0, a16, Ntot, 256, SK, SK, 0, 0,
        nullptr, nullptr, nullptr, nullptr);
    hgemm<_Float16,false,false,true><<<dim3(cdiv(Ntot,128), 6, 2), blk, 0, stream>>>(
        a16, wih16, b_ih, gi, Ntot, 768, 256, 256, 0, 0,
        h16, whh16, b_hh, gh);
    gru_gate_k<<<cdiv(Ntot*64,256), blk, 0, stream>>>(gi, gh, h, h16);
  }

  // 4. conv-head weight repacks (conv-phase spare of big)
  repack16_k<<<cdiv(256*256*3,256), blk, 0, stream>>>(conv1_w,  wk1,  256, 256, 3);
  repack16_k<<<cdiv(384*384*3,256), blk, 0, stream>>>(convc1_w, wkc1, 384, 384, 3);
  repack16_k<<<cdiv(384*384*2,256), blk, 0, stream>>>(convc2_w, wkc2, 384, 384, 2);
  cvt_k<<<cdiv(256*256/4,256), blk, 0, stream>>>(conv2_w, c2w16, 256*256);

  // 5. Y head: conv1(K=3) -> pool3 -> conv2(K=1) -> pool2
  hgemm<_Float16,true,true,false><<<dim3(cdiv(Bg*511,128), 2), blk, 0, stream>>>(
      h16, wk1, conv1_b, y1, Bg*511, 256, 768, 256, 511, NNg,
      nullptr, nullptr, nullptr, nullptr);
  maxpool_k<_Float16,_Float16><<<cdiv(Bg*255*256,256), blk, 0, stream>>>(y1, p1, 511, 255, 256, 3);
  hgemm<float,true,false,false><<<dim3(cdiv(Bg*255,128), 2), blk, 0, stream>>>(
      p1, c2w16, conv2_b, y2, Bg*255, 256, 256, 256, 0, 0,
      nullptr, nullptr, nullptr, nullptr);
  maxpool_k<float,float><<<cdiv(Bg*127*256,256), blk, 0, stream>>>(y2, Y2, 255, 127, 256, 2);

  // 6. Z head: cb16=concat(h16,(f16)feature); convc1(K=3) -> pool3 -> convc2(K=2) -> pool2
  build_cb16_k<<<cdiv(Ntot*CATF,256), blk, 0, stream>>>(h16, feature, cb16);
  hgemm<_Float16,true,true,false><<<dim3(cdiv(Bg*511,128), 3), blk, 0, stream>>>(
      cb16, wkc1, convc1_b, z1, Bg*511, 384, 1152, 384, 511, NNg,
      nullptr, nullptr, nullptr, nullptr);
  maxpool_k<_Float16,_Float16><<<cdiv(Bg*255*384,256), blk, 0, stream>>>(z1, pz1, 511, 255, 384, 3);
  hgemm<float,true,true,false><<<dim3(cdiv(Bg*254,128), 3), blk, 0, stream>>>(
      pz1, wkc2, convc2_b, z2, Bg*254, 384, 768, 384, 254, 255,
      nullptr, nullptr, nullptr, nullptr);
  maxpool_k<float,float><<<cdiv(Bg*127*384,256), blk, 0, stream>>>(z2, Z2, 254, 127, 384, 2);

  // 7. head
  head_k<<<Bg, 128, 0, stream>>>(Y2, Z2, mlpy_w, mlpy_b, mlpz_w, mlpz_b, out);
}